// Round 1
// baseline (556.506 us; speedup 1.0000x reference)
//
#include <hip/hip_runtime.h>

#define NPTS 65536
#define MTOT 1048576            // NPTS * NS
#define EPSb 1e-5f

// workspace layout (float element offsets)
#define XQ_OFF  0u              // [NPTS*64]
#define XK_OFF  4194304u        // [NPTS*64]
#define XV_OFF  8388608u        // [NPTS*64]
#define W1P_OFF 12582912u       // [NPTS*16*8]
#define ST_OFF  20971520u       // stats: 0..2 s1, 3..5 q1, 6..69 s2, 70..133 q2, 134..141 s3, 142..149 q3

// ---------------------------------------------------------------------------
// K1: xq/xk/xv projections + BN1 (rel_p @ Wp1) statistics
// block=256 (4 waves), block handles 64 points; grid=1024
// ---------------------------------------------------------------------------
__global__ __launch_bounds__(256) void k1_proj_bn1(
    const float* __restrict__ p, const float* __restrict__ x, const int* __restrict__ idx,
    const float* __restrict__ Wq, const float* __restrict__ bq,
    const float* __restrict__ Wk, const float* __restrict__ bk,
    const float* __restrict__ Wv, const float* __restrict__ bv,
    const float* __restrict__ Wp1, const float* __restrict__ bp1,
    float* __restrict__ ws)
{
    __shared__ float sW[3][64][64];
    __shared__ float sred[6];
    const int tid = threadIdx.x;
    for (int i = tid; i < 4096; i += 256) {
        sW[0][i >> 6][i & 63] = Wq[i];
        sW[1][i >> 6][i & 63] = Wk[i];
        sW[2][i >> 6][i & 63] = Wv[i];
    }
    if (tid < 6) sred[tid] = 0.0f;
    __syncthreads();

    const int lane = tid & 63;
    const int grp  = tid >> 6;
    const int base = blockIdx.x * 64;
    const float bqc = bq[lane], bkc = bk[lane], bvc = bv[lane];
    float* xq = ws + XQ_OFF;
    float* xk = ws + XK_OFF;
    float* xv = ws + XV_OFF;

    // 4 tiles of 4 points per wave: amortize the LDS weight reads 4x
    for (int tile = 0; tile < 4; ++tile) {
        const int n0 = base + grp * 16 + tile * 4;
        float x0 = x[(n0 + 0) * 64 + lane];
        float x1 = x[(n0 + 1) * 64 + lane];
        float x2 = x[(n0 + 2) * 64 + lane];
        float x3 = x[(n0 + 3) * 64 + lane];
        float aq0 = bqc, aq1 = bqc, aq2 = bqc, aq3 = bqc;
        float ak0 = bkc, ak1 = bkc, ak2 = bkc, ak3 = bkc;
        float av0 = bvc, av1 = bvc, av2 = bvc, av3 = bvc;
#pragma unroll
        for (int k = 0; k < 64; ++k) {
            const float wq  = sW[0][k][lane];
            const float wk_ = sW[1][k][lane];
            const float wv_ = sW[2][k][lane];
            const float b0 = __shfl(x0, k, 64);
            const float b1 = __shfl(x1, k, 64);
            const float b2 = __shfl(x2, k, 64);
            const float b3 = __shfl(x3, k, 64);
            aq0 = fmaf(b0, wq, aq0); ak0 = fmaf(b0, wk_, ak0); av0 = fmaf(b0, wv_, av0);
            aq1 = fmaf(b1, wq, aq1); ak1 = fmaf(b1, wk_, ak1); av1 = fmaf(b1, wv_, av1);
            aq2 = fmaf(b2, wq, aq2); ak2 = fmaf(b2, wk_, ak2); av2 = fmaf(b2, wv_, av2);
            aq3 = fmaf(b3, wq, aq3); ak3 = fmaf(b3, wk_, ak3); av3 = fmaf(b3, wv_, av3);
        }
        xq[(n0 + 0) * 64 + lane] = aq0; xq[(n0 + 1) * 64 + lane] = aq1;
        xq[(n0 + 2) * 64 + lane] = aq2; xq[(n0 + 3) * 64 + lane] = aq3;
        xk[(n0 + 0) * 64 + lane] = ak0; xk[(n0 + 1) * 64 + lane] = ak1;
        xk[(n0 + 2) * 64 + lane] = ak2; xk[(n0 + 3) * 64 + lane] = ak3;
        xv[(n0 + 0) * 64 + lane] = av0; xv[(n0 + 1) * 64 + lane] = av1;
        xv[(n0 + 2) * 64 + lane] = av2; xv[(n0 + 3) * 64 + lane] = av3;
    }

    // BN1 stats for this block's 1024 (n,j) pairs
    const float w00 = Wp1[0], w01 = Wp1[1], w02 = Wp1[2];
    const float w10 = Wp1[3], w11 = Wp1[4], w12 = Wp1[5];
    const float w20 = Wp1[6], w21 = Wp1[7], w22 = Wp1[8];
    const float c0 = bp1[0], c1 = bp1[1], c2 = bp1[2];
    float s0 = 0, s1 = 0, s2 = 0, q0 = 0, q1 = 0, q2 = 0;
#pragma unroll
    for (int m = 0; m < 4; ++m) {
        const int pl = tid + m * 256;            // 0..1023
        const int n  = base + (pl >> 4);
        const int nb = idx[base * 16 + pl];
        const float r0 = p[nb * 3 + 0] - p[n * 3 + 0];
        const float r1 = p[nb * 3 + 1] - p[n * 3 + 1];
        const float r2 = p[nb * 3 + 2] - p[n * 3 + 2];
        const float t0 = c0 + r0 * w00 + r1 * w10 + r2 * w20;
        const float t1 = c1 + r0 * w01 + r1 * w11 + r2 * w21;
        const float t2 = c2 + r0 * w02 + r1 * w12 + r2 * w22;
        s0 += t0; s1 += t1; s2 += t2;
        q0 += t0 * t0; q1 += t1 * t1; q2 += t2 * t2;
    }
    atomicAdd(&sred[0], s0); atomicAdd(&sred[1], s1); atomicAdd(&sred[2], s2);
    atomicAdd(&sred[3], q0); atomicAdd(&sred[4], q1); atomicAdd(&sred[5], q2);
    __syncthreads();
    if (tid < 6) atomicAdd(&ws[ST_OFF + tid], sred[tid]);
}

// ---------------------------------------------------------------------------
// K2: BN2 statistics over w0 = xk[idx] - xq + pr   (lane = channel)
// wave handles 256 pairs (16 points); grid=1024 x 256 -> 4096 waves
// ---------------------------------------------------------------------------
__global__ __launch_bounds__(256) void k2_bn2(
    const float* __restrict__ p, const int* __restrict__ idx,
    const float* __restrict__ Wp1, const float* __restrict__ bp1,
    const float* __restrict__ gp, const float* __restrict__ bp_bn,
    const float* __restrict__ Wp2, const float* __restrict__ bp2,
    float* __restrict__ ws)
{
    __shared__ float ss[64], sq[64];
    const int tid = threadIdx.x;
    const int lane = tid & 63;
    const int gw = blockIdx.x * 4 + (tid >> 6);
    if (tid < 64) { ss[tid] = 0.0f; sq[tid] = 0.0f; }

    const float invM = 1.0f / (float)MTOT;
    float A1[3], B1[3];
#pragma unroll
    for (int a = 0; a < 3; ++a) {
        const float mean = ws[ST_OFF + a] * invM;
        const float var  = ws[ST_OFF + 3 + a] * invM - mean * mean;
        const float sc = gp[a] * rsqrtf(var + EPSb);
        A1[a] = sc; B1[a] = bp_bn[a] - mean * sc;
    }
    const float w00 = Wp1[0], w01 = Wp1[1], w02 = Wp1[2];
    const float w10 = Wp1[3], w11 = Wp1[4], w12 = Wp1[5];
    const float w20 = Wp1[6], w21 = Wp1[7], w22 = Wp1[8];
    const float c0 = bp1[0], c1 = bp1[1], c2 = bp1[2];
    const float wp20 = Wp2[lane], wp21 = Wp2[64 + lane], wp22 = Wp2[128 + lane];
    const float bp2c = bp2[lane];
    const float* xq = ws + XQ_OFF;
    const float* xk = ws + XK_OFF;

    float s = 0.0f, q = 0.0f;
    for (int nn = 0; nn < 16; ++nn) {
        const int n = gw * 16 + nn;
        const float pn0 = p[n * 3 + 0], pn1 = p[n * 3 + 1], pn2 = p[n * 3 + 2];
        const float xqc = xq[n * 64 + lane];
#pragma unroll
        for (int j = 0; j < 16; ++j) {
            const int nb = idx[n * 16 + j];
            const float r0 = p[nb * 3 + 0] - pn0;
            const float r1 = p[nb * 3 + 1] - pn1;
            const float r2 = p[nb * 3 + 2] - pn2;
            float t0 = c0 + r0 * w00 + r1 * w10 + r2 * w20;
            float t1 = c1 + r0 * w01 + r1 * w11 + r2 * w21;
            float t2 = c2 + r0 * w02 + r1 * w12 + r2 * w22;
            t0 = fmaxf(fmaf(t0, A1[0], B1[0]), 0.0f);
            t1 = fmaxf(fmaf(t1, A1[1], B1[1]), 0.0f);
            t2 = fmaxf(fmaf(t2, A1[2], B1[2]), 0.0f);
            const float prc = bp2c + t0 * wp20 + t1 * wp21 + t2 * wp22;
            const float w0 = xk[nb * 64 + lane] - xqc + prc;
            s += w0; q = fmaf(w0, w0, q);
        }
    }
    __syncthreads();
    atomicAdd(&ss[lane], s); atomicAdd(&sq[lane], q);
    __syncthreads();
    if (tid < 64) {
        atomicAdd(&ws[ST_OFF + 6 + tid], ss[tid]);
        atomicAdd(&ws[ST_OFF + 70 + tid], sq[tid]);
    }
}

// ---------------------------------------------------------------------------
// K3: w1' = relu(bn2(w0)) @ Ww1 + bw1  (store [NPTS*16,8]) + BN3 statistics
// phase1: lane=channel compute V into LDS (pad 65 -> conflict-free)
// phase2: lane=pair LDS matmul 64->8
// ---------------------------------------------------------------------------
__global__ __launch_bounds__(256) void k3_w1_bn3(
    const float* __restrict__ p, const int* __restrict__ idx,
    const float* __restrict__ Wp1, const float* __restrict__ bp1,
    const float* __restrict__ gp, const float* __restrict__ bp_bn,
    const float* __restrict__ Wp2, const float* __restrict__ bp2,
    const float* __restrict__ gw1, const float* __restrict__ bw1_bn,
    const float* __restrict__ Ww1, const float* __restrict__ bw1,
    float* __restrict__ ws)
{
    __shared__ __align__(16) float sV[4][32][65];
    __shared__ __align__(16) float sB[64][8];
    __shared__ float s3r[8], q3r[8];
    const int tid = threadIdx.x;
    const int lane = tid & 63;
    const int wid = tid >> 6;
    const int gw = blockIdx.x * 4 + wid;
    for (int i = tid; i < 512; i += 256) ((float*)sB)[i] = Ww1[i];
    if (tid < 8) { s3r[tid] = 0.0f; q3r[tid] = 0.0f; }

    const float invM = 1.0f / (float)MTOT;
    float A1[3], B1[3];
#pragma unroll
    for (int a = 0; a < 3; ++a) {
        const float mean = ws[ST_OFF + a] * invM;
        const float var  = ws[ST_OFF + 3 + a] * invM - mean * mean;
        const float sc = gp[a] * rsqrtf(var + EPSb);
        A1[a] = sc; B1[a] = bp_bn[a] - mean * sc;
    }
    const float mean2 = ws[ST_OFF + 6 + lane] * invM;
    const float var2  = ws[ST_OFF + 70 + lane] * invM - mean2 * mean2;
    const float A2 = gw1[lane] * rsqrtf(var2 + EPSb);
    const float B2 = bw1_bn[lane] - mean2 * A2;

    const float w00 = Wp1[0], w01 = Wp1[1], w02 = Wp1[2];
    const float w10 = Wp1[3], w11 = Wp1[4], w12 = Wp1[5];
    const float w20 = Wp1[6], w21 = Wp1[7], w22 = Wp1[8];
    const float c0 = bp1[0], c1 = bp1[1], c2 = bp1[2];
    const float wp20 = Wp2[lane], wp21 = Wp2[64 + lane], wp22 = Wp2[128 + lane];
    const float bp2c = bp2[lane];
    float bw1r[8];
#pragma unroll
    for (int t = 0; t < 8; ++t) bw1r[t] = bw1[t];

    const float* xq = ws + XQ_OFF;
    const float* xk = ws + XK_OFF;
    float bs[8] = {0, 0, 0, 0, 0, 0, 0, 0};
    float bq2[8] = {0, 0, 0, 0, 0, 0, 0, 0};
    __syncthreads();

    for (int cc = 0; cc < 8; ++cc) {
        // phase 1: 32 pairs (2 points) -> V in LDS
        for (int nn = 0; nn < 2; ++nn) {
            const int n = gw * 16 + cc * 2 + nn;
            const float pn0 = p[n * 3 + 0], pn1 = p[n * 3 + 1], pn2 = p[n * 3 + 2];
            const float xqc = xq[n * 64 + lane];
#pragma unroll
            for (int j = 0; j < 16; ++j) {
                const int nb = idx[n * 16 + j];
                const float r0 = p[nb * 3 + 0] - pn0;
                const float r1 = p[nb * 3 + 1] - pn1;
                const float r2 = p[nb * 3 + 2] - pn2;
                float t0 = c0 + r0 * w00 + r1 * w10 + r2 * w20;
                float t1 = c1 + r0 * w01 + r1 * w11 + r2 * w21;
                float t2 = c2 + r0 * w02 + r1 * w12 + r2 * w22;
                t0 = fmaxf(fmaf(t0, A1[0], B1[0]), 0.0f);
                t1 = fmaxf(fmaf(t1, A1[1], B1[1]), 0.0f);
                t2 = fmaxf(fmaf(t2, A1[2], B1[2]), 0.0f);
                const float prc = bp2c + t0 * wp20 + t1 * wp21 + t2 * wp22;
                const float w0 = xk[nb * 64 + lane] - xqc + prc;
                sV[wid][nn * 16 + j][lane] = fmaxf(fmaf(w0, A2, B2), 0.0f);
            }
        }
        __syncthreads();
        // phase 2: [32,64] @ [64,8]; lanes 0..31 pair p half c=0..31, 32..63 half c=32..63
        const int pp = lane & 31;
        const int half = lane >> 5;
        float acc[8] = {0, 0, 0, 0, 0, 0, 0, 0};
#pragma unroll
        for (int k = 0; k < 32; ++k) {
            const int ci = half * 32 + k;
            const float v = sV[wid][pp][ci];
            const float4 bb0 = *(const float4*)&sB[ci][0];
            const float4 bb1 = *(const float4*)&sB[ci][4];
            acc[0] = fmaf(v, bb0.x, acc[0]); acc[1] = fmaf(v, bb0.y, acc[1]);
            acc[2] = fmaf(v, bb0.z, acc[2]); acc[3] = fmaf(v, bb0.w, acc[3]);
            acc[4] = fmaf(v, bb1.x, acc[4]); acc[5] = fmaf(v, bb1.y, acc[5]);
            acc[6] = fmaf(v, bb1.z, acc[6]); acc[7] = fmaf(v, bb1.w, acc[7]);
        }
#pragma unroll
        for (int t = 0; t < 8; ++t) acc[t] += __shfl_xor(acc[t], 32, 64);
        if (lane < 32) {
            const int pair = gw * 256 + cc * 32 + lane;
            float o[8];
#pragma unroll
            for (int t = 0; t < 8; ++t) {
                o[t] = acc[t] + bw1r[t];
                bs[t] += o[t];
                bq2[t] = fmaf(o[t], o[t], bq2[t]);
            }
            float4* dst = (float4*)(ws + W1P_OFF + (unsigned)pair * 8u);
            dst[0] = make_float4(o[0], o[1], o[2], o[3]);
            dst[1] = make_float4(o[4], o[5], o[6], o[7]);
        }
        __syncthreads();
    }
    if (lane < 32) {
#pragma unroll
        for (int t = 0; t < 8; ++t) { atomicAdd(&s3r[t], bs[t]); atomicAdd(&q3r[t], bq2[t]); }
    }
    __syncthreads();
    if (tid < 8) {
        atomicAdd(&ws[ST_OFF + 134 + tid], s3r[tid]);
        atomicAdd(&ws[ST_OFF + 142 + tid], q3r[tid]);
    }
}

// ---------------------------------------------------------------------------
// K4: bn3 -> relu -> @Ww2 -> softmax over neighbors -> weighted aggregation
// one wave per point (lane = out channel), 16 points per wave
// ---------------------------------------------------------------------------
__global__ __launch_bounds__(256) void k4_final(
    const float* __restrict__ p, const int* __restrict__ idx,
    const float* __restrict__ Wp1, const float* __restrict__ bp1,
    const float* __restrict__ gp, const float* __restrict__ bp_bn,
    const float* __restrict__ Wp2, const float* __restrict__ bp2,
    const float* __restrict__ gw2, const float* __restrict__ bw2_bn,
    const float* __restrict__ Ww2, const float* __restrict__ bw2,
    const float* __restrict__ ws, float* __restrict__ out)
{
    __shared__ int   snb[4][16];
    __shared__ float sq3[4][16][4];
    __shared__ float sv3[4][16][8];
    __shared__ float sw2[4][16][8];
    const int tid = threadIdx.x;
    const int lane = tid & 63;
    const int wid = tid >> 6;
    const int gw = blockIdx.x * 4 + wid;
    const int tt = lane & 7;

    const float invM = 1.0f / (float)MTOT;
    float A1[3], B1[3];
#pragma unroll
    for (int a = 0; a < 3; ++a) {
        const float mean = ws[ST_OFF + a] * invM;
        const float var  = ws[ST_OFF + 3 + a] * invM - mean * mean;
        const float sc = gp[a] * rsqrtf(var + EPSb);
        A1[a] = sc; B1[a] = bp_bn[a] - mean * sc;
    }
    const float mean3 = ws[ST_OFF + 134 + tt] * invM;
    const float var3  = ws[ST_OFF + 142 + tt] * invM - mean3 * mean3;
    const float A3 = gw2[tt] * rsqrtf(var3 + EPSb);
    const float B3 = bw2_bn[tt] - mean3 * A3;
    float ww2c[8];
#pragma unroll
    for (int u = 0; u < 8; ++u) ww2c[u] = Ww2[u * 8 + tt];
    const float bw2c = bw2[tt];

    const float w00 = Wp1[0], w01 = Wp1[1], w02 = Wp1[2];
    const float w10 = Wp1[3], w11 = Wp1[4], w12 = Wp1[5];
    const float w20 = Wp1[6], w21 = Wp1[7], w22 = Wp1[8];
    const float c0 = bp1[0], c1 = bp1[1], c2 = bp1[2];
    const float wp20 = Wp2[lane], wp21 = Wp2[64 + lane], wp22 = Wp2[128 + lane];
    const float bp2c = bp2[lane];
    const float* xv  = ws + XV_OFF;
    const float* w1p = ws + W1P_OFF;

    for (int it = 0; it < 16; ++it) {
        const int n = gw * 16 + it;
        if (lane < 16) {
            const int nb = idx[n * 16 + lane];
            snb[wid][lane] = nb;
            const float r0 = p[nb * 3 + 0] - p[n * 3 + 0];
            const float r1 = p[nb * 3 + 1] - p[n * 3 + 1];
            const float r2 = p[nb * 3 + 2] - p[n * 3 + 2];
            float t0 = c0 + r0 * w00 + r1 * w10 + r2 * w20;
            float t1 = c1 + r0 * w01 + r1 * w11 + r2 * w21;
            float t2 = c2 + r0 * w02 + r1 * w12 + r2 * w22;
            t0 = fmaxf(fmaf(t0, A1[0], B1[0]), 0.0f);
            t1 = fmaxf(fmaf(t1, A1[1], B1[1]), 0.0f);
            t2 = fmaxf(fmaf(t2, A1[2], B1[2]), 0.0f);
            sq3[wid][lane][0] = t0; sq3[wid][lane][1] = t1; sq3[wid][lane][2] = t2;
        }
        {
            const float v1 = w1p[n * 128 + lane];
            const float v2 = w1p[n * 128 + 64 + lane];
            sv3[wid][lane >> 3][tt]       = fmaxf(fmaf(v1, A3, B3), 0.0f);
            sv3[wid][(lane >> 3) + 8][tt] = fmaxf(fmaf(v2, A3, B3), 0.0f);
        }
        __syncthreads();
        {
            const int j1 = lane >> 3;
            float a0 = bw2c, a1 = bw2c;
#pragma unroll
            for (int u = 0; u < 8; ++u) {
                a0 = fmaf(sv3[wid][j1][u], ww2c[u], a0);
                a1 = fmaf(sv3[wid][j1 + 8][u], ww2c[u], a1);
            }
            sw2[wid][j1][tt] = a0;
            sw2[wid][j1 + 8][tt] = a1;
        }
        __syncthreads();
        float mx = -1e30f;
#pragma unroll
        for (int j = 0; j < 16; ++j) mx = fmaxf(mx, sw2[wid][j][tt]);
        float e[16];
        float sum = 0.0f;
#pragma unroll
        for (int j = 0; j < 16; ++j) { e[j] = __expf(sw2[wid][j][tt] - mx); sum += e[j]; }
        const float inv = 1.0f / sum;
        float acc = 0.0f;
#pragma unroll
        for (int j = 0; j < 16; ++j) {
            const int nb = snb[wid][j];
            const float prc = bp2c + sq3[wid][j][0] * wp20 + sq3[wid][j][1] * wp21 + sq3[wid][j][2] * wp22;
            acc += (xv[nb * 64 + lane] + prc) * (e[j] * inv);
        }
        out[n * 64 + lane] = acc;
        __syncthreads();
    }
}

extern "C" void kernel_launch(void* const* d_in, const int* in_sizes, int n_in,
                              void* d_out, int out_size, void* d_ws, size_t ws_size,
                              hipStream_t stream)
{
    const float* p      = (const float*)d_in[0];
    const float* x      = (const float*)d_in[1];
    const int*   idx    = (const int*)d_in[2];
    const float* Wq     = (const float*)d_in[3];
    const float* bq     = (const float*)d_in[4];
    const float* Wk     = (const float*)d_in[5];
    const float* bk     = (const float*)d_in[6];
    const float* Wv     = (const float*)d_in[7];
    const float* bv     = (const float*)d_in[8];
    const float* Wp1    = (const float*)d_in[9];
    const float* bp1    = (const float*)d_in[10];
    const float* gp     = (const float*)d_in[11];
    const float* bp_bn  = (const float*)d_in[12];
    const float* Wp2    = (const float*)d_in[13];
    const float* bp2    = (const float*)d_in[14];
    const float* gw1    = (const float*)d_in[15];
    const float* bw1_bn = (const float*)d_in[16];
    const float* Ww1    = (const float*)d_in[17];
    const float* bw1    = (const float*)d_in[18];
    const float* gw2    = (const float*)d_in[19];
    const float* bw2_bn = (const float*)d_in[20];
    const float* Ww2    = (const float*)d_in[21];
    const float* bw2    = (const float*)d_in[22];
    float* ws  = (float*)d_ws;
    float* out = (float*)d_out;
    (void)in_sizes; (void)n_in; (void)out_size; (void)ws_size;

    // zero the stats accumulators (ws is poisoned 0xAA before every launch)
    hipMemsetAsync((char*)d_ws + (size_t)ST_OFF * 4, 0, 150 * sizeof(float), stream);

    k1_proj_bn1<<<1024, 256, 0, stream>>>(p, x, idx, Wq, bq, Wk, bk, Wv, bv, Wp1, bp1, ws);
    k2_bn2<<<1024, 256, 0, stream>>>(p, idx, Wp1, bp1, gp, bp_bn, Wp2, bp2, ws);
    k3_w1_bn3<<<1024, 256, 0, stream>>>(p, idx, Wp1, bp1, gp, bp_bn, Wp2, bp2,
                                        gw1, bw1_bn, Ww1, bw1, ws);
    k4_final<<<1024, 256, 0, stream>>>(p, idx, Wp1, bp1, gp, bp_bn, Wp2, bp2,
                                       gw2, bw2_bn, Ww2, bw2, ws, out);
}

// Round 2
// 460.091 us; speedup vs baseline: 1.2096x; 1.2096x over previous
//
#include <hip/hip_runtime.h>

typedef unsigned short u16;

#define NPTS 65536
#define MTOT 1048576            // NPTS * NS
#define EPSb 1e-5f

// ---- workspace layout ----
// float-offsets from ws base:
#define XQ_OFF  0u              // f32 [NPTS,64]            16 MB
#define T_OFF   4194304u        // f32 [MTOT,3] raw bn1 in  12 MB
#define W1P_OFF 7340032u        // f32 [MTOT,8]             32 MB
#define ST_OFF  15728640u       // f32 [150] stats
// ushort-offsets from ws base (byte off 62,915,584; 256B aligned):
#define XK_US   31457792u       // bf16 [NPTS,64]            8 MB
#define XV_US   35652096u       // bf16 [NPTS,64]            8 MB
#define W0_US   39846400u       // bf16 [MTOT,64]          128 MB
// total ws usage ~214 MB

__device__ __forceinline__ float bf2f(u16 h) {
    return __uint_as_float(((unsigned)h) << 16);
}
__device__ __forceinline__ u16 f2bf(float f) {
    unsigned u = __float_as_uint(f);
    u += 0x7fffu + ((u >> 16) & 1u);      // round-to-nearest-even
    return (u16)(u >> 16);
}

// ---------------------------------------------------------------------------
// K1: xq/xk/xv projections (xk/xv stored bf16) + BN1 stats + store raw T
// ---------------------------------------------------------------------------
__global__ __launch_bounds__(256) void k1_proj_bn1(
    const float* __restrict__ p, const float* __restrict__ x, const int* __restrict__ idx,
    const float* __restrict__ Wq, const float* __restrict__ bq,
    const float* __restrict__ Wk, const float* __restrict__ bk,
    const float* __restrict__ Wv, const float* __restrict__ bv,
    const float* __restrict__ Wp1, const float* __restrict__ bp1,
    float* __restrict__ ws)
{
    u16* wsu = (u16*)ws;
    __shared__ float sW[3][64][64];
    __shared__ float sred[6];
    const int tid = threadIdx.x;
    for (int i = tid; i < 4096; i += 256) {
        sW[0][i >> 6][i & 63] = Wq[i];
        sW[1][i >> 6][i & 63] = Wk[i];
        sW[2][i >> 6][i & 63] = Wv[i];
    }
    if (tid < 6) sred[tid] = 0.0f;
    __syncthreads();

    const int lane = tid & 63;
    const int grp  = tid >> 6;
    const int base = blockIdx.x * 64;
    const float bqc = bq[lane], bkc = bk[lane], bvc = bv[lane];
    float* xq  = ws + XQ_OFF;
    u16*  xkb  = wsu + XK_US;
    u16*  xvb  = wsu + XV_US;

    for (int tile = 0; tile < 4; ++tile) {
        const int n0 = base + grp * 16 + tile * 4;
        float x0 = x[(n0 + 0) * 64 + lane];
        float x1 = x[(n0 + 1) * 64 + lane];
        float x2 = x[(n0 + 2) * 64 + lane];
        float x3 = x[(n0 + 3) * 64 + lane];
        float aq0 = bqc, aq1 = bqc, aq2 = bqc, aq3 = bqc;
        float ak0 = bkc, ak1 = bkc, ak2 = bkc, ak3 = bkc;
        float av0 = bvc, av1 = bvc, av2 = bvc, av3 = bvc;
#pragma unroll
        for (int k = 0; k < 64; ++k) {
            const float wq  = sW[0][k][lane];
            const float wk_ = sW[1][k][lane];
            const float wv_ = sW[2][k][lane];
            const float b0 = __shfl(x0, k, 64);
            const float b1 = __shfl(x1, k, 64);
            const float b2 = __shfl(x2, k, 64);
            const float b3 = __shfl(x3, k, 64);
            aq0 = fmaf(b0, wq, aq0); ak0 = fmaf(b0, wk_, ak0); av0 = fmaf(b0, wv_, av0);
            aq1 = fmaf(b1, wq, aq1); ak1 = fmaf(b1, wk_, ak1); av1 = fmaf(b1, wv_, av1);
            aq2 = fmaf(b2, wq, aq2); ak2 = fmaf(b2, wk_, ak2); av2 = fmaf(b2, wv_, av2);
            aq3 = fmaf(b3, wq, aq3); ak3 = fmaf(b3, wk_, ak3); av3 = fmaf(b3, wv_, av3);
        }
        xq[(n0 + 0) * 64 + lane] = aq0; xq[(n0 + 1) * 64 + lane] = aq1;
        xq[(n0 + 2) * 64 + lane] = aq2; xq[(n0 + 3) * 64 + lane] = aq3;
        xkb[(n0 + 0) * 64 + lane] = f2bf(ak0); xkb[(n0 + 1) * 64 + lane] = f2bf(ak1);
        xkb[(n0 + 2) * 64 + lane] = f2bf(ak2); xkb[(n0 + 3) * 64 + lane] = f2bf(ak3);
        xvb[(n0 + 0) * 64 + lane] = f2bf(av0); xvb[(n0 + 1) * 64 + lane] = f2bf(av1);
        xvb[(n0 + 2) * 64 + lane] = f2bf(av2); xvb[(n0 + 3) * 64 + lane] = f2bf(av3);
    }

    // BN1 stats + store raw T for this block's 1024 pairs
    const float w00 = Wp1[0], w01 = Wp1[1], w02 = Wp1[2];
    const float w10 = Wp1[3], w11 = Wp1[4], w12 = Wp1[5];
    const float w20 = Wp1[6], w21 = Wp1[7], w22 = Wp1[8];
    const float c0 = bp1[0], c1 = bp1[1], c2 = bp1[2];
    float s0 = 0, s1 = 0, s2 = 0, q0 = 0, q1 = 0, q2 = 0;
#pragma unroll
    for (int m = 0; m < 4; ++m) {
        const int pl = tid + m * 256;            // 0..1023
        const int n  = base + (pl >> 4);
        const unsigned gpair = (unsigned)(base * 16 + pl);
        const int nb = idx[gpair];
        const float r0 = p[nb * 3 + 0] - p[n * 3 + 0];
        const float r1 = p[nb * 3 + 1] - p[n * 3 + 1];
        const float r2 = p[nb * 3 + 2] - p[n * 3 + 2];
        const float t0 = c0 + r0 * w00 + r1 * w10 + r2 * w20;
        const float t1 = c1 + r0 * w01 + r1 * w11 + r2 * w21;
        const float t2 = c2 + r0 * w02 + r1 * w12 + r2 * w22;
        ws[T_OFF + gpair * 3u + 0u] = t0;
        ws[T_OFF + gpair * 3u + 1u] = t1;
        ws[T_OFF + gpair * 3u + 2u] = t2;
        s0 += t0; s1 += t1; s2 += t2;
        q0 += t0 * t0; q1 += t1 * t1; q2 += t2 * t2;
    }
    atomicAdd(&sred[0], s0); atomicAdd(&sred[1], s1); atomicAdd(&sred[2], s2);
    atomicAdd(&sred[3], q0); atomicAdd(&sred[4], q1); atomicAdd(&sred[5], q2);
    __syncthreads();
    if (tid < 6) atomicAdd(&ws[ST_OFF + tid], sred[tid]);
}

// ---------------------------------------------------------------------------
// K2: w0 = xk[idx] - xq + pr ; store w0 bf16 ; BN2 stats
// wave = 16 points, lane = channel; batch-issued gathers + next-point prefetch
// ---------------------------------------------------------------------------
__global__ __launch_bounds__(256) void k2_bn2(
    const int* __restrict__ idx,
    const float* __restrict__ gp, const float* __restrict__ bp_bn,
    const float* __restrict__ Wp2, const float* __restrict__ bp2,
    float* __restrict__ ws)
{
    u16* wsu = (u16*)ws;
    __shared__ float ss[64], sq[64];
    const int tid = threadIdx.x;
    const int lane = tid & 63;
    const int gw = blockIdx.x * 4 + (tid >> 6);
    if (tid < 64) { ss[tid] = 0.0f; sq[tid] = 0.0f; }

    const float invM = 1.0f / (float)MTOT;
    float A1[3], B1[3];
#pragma unroll
    for (int a = 0; a < 3; ++a) {
        const float mean = ws[ST_OFF + a] * invM;
        const float var  = ws[ST_OFF + 3 + a] * invM - mean * mean;
        const float sc = gp[a] * rsqrtf(var + EPSb);
        A1[a] = sc; B1[a] = bp_bn[a] - mean * sc;
    }
    const float wp20 = Wp2[lane], wp21 = Wp2[64 + lane], wp22 = Wp2[128 + lane];
    const float bp2c = bp2[lane];
    const float* xq  = ws + XQ_OFF;
    const float* T   = ws + T_OFF;
    const u16*  xkb  = wsu + XK_US;
    u16*        w0b  = wsu + W0_US;

    float s = 0.0f, q = 0.0f;
    const int n0 = gw * 16;
    int   il  = (lane < 16) ? idx[n0 * 16 + lane] : 0;
    float tl  = (lane < 48) ? T[(unsigned)n0 * 48u + lane] : 0.0f;
    float xqc = xq[(unsigned)n0 * 64u + lane];

    for (int nn = 0; nn < 16; ++nn) {
        const int n = n0 + nn;
        const int   ilc = il;
        const float tlc = tl;
        const float xqq = xqc;
        if (nn < 15) {
            const int nx = n + 1;
            il  = (lane < 16) ? idx[nx * 16 + lane] : 0;
            tl  = (lane < 48) ? T[(unsigned)nx * 48u + lane] : 0.0f;
            xqc = xq[(unsigned)nx * 64u + lane];
        }
        int nb[16];
#pragma unroll
        for (int j = 0; j < 16; ++j) nb[j] = __shfl(ilc, j, 64);
        u16 kr[16];
#pragma unroll
        for (int j = 0; j < 16; ++j) kr[j] = xkb[(unsigned)nb[j] * 64u + lane];
#pragma unroll
        for (int j = 0; j < 16; ++j) {
            float t0 = __shfl(tlc, 3 * j + 0, 64);
            float t1 = __shfl(tlc, 3 * j + 1, 64);
            float t2 = __shfl(tlc, 3 * j + 2, 64);
            t0 = fmaxf(fmaf(t0, A1[0], B1[0]), 0.0f);
            t1 = fmaxf(fmaf(t1, A1[1], B1[1]), 0.0f);
            t2 = fmaxf(fmaf(t2, A1[2], B1[2]), 0.0f);
            const float prc = bp2c + t0 * wp20 + t1 * wp21 + t2 * wp22;
            const float w0 = bf2f(kr[j]) - xqq + prc;
            s += w0; q = fmaf(w0, w0, q);
            w0b[(unsigned)(n * 16 + j) * 64u + lane] = f2bf(w0);
        }
    }
    __syncthreads();
    atomicAdd(&ss[lane], s); atomicAdd(&sq[lane], q);
    __syncthreads();
    if (tid < 64) {
        atomicAdd(&ws[ST_OFF + 6 + tid], ss[tid]);
        atomicAdd(&ws[ST_OFF + 70 + tid], sq[tid]);
    }
}

// ---------------------------------------------------------------------------
// K3: w1' = relu(bn2(w0)) @ Ww1 + bw1 (streaming read of stored w0) + BN3 stats
// ---------------------------------------------------------------------------
__global__ __launch_bounds__(256) void k3_w1_bn3(
    const float* __restrict__ gw1, const float* __restrict__ bw1_bn,
    const float* __restrict__ Ww1, const float* __restrict__ bw1,
    float* __restrict__ ws)
{
    u16* wsu = (u16*)ws;
    __shared__ __align__(16) float sV[4][32][65];
    __shared__ __align__(16) float sB[64][8];
    __shared__ float s3r[8], q3r[8];
    const int tid = threadIdx.x;
    const int lane = tid & 63;
    const int wid = tid >> 6;
    const int gw = blockIdx.x * 4 + wid;
    for (int i = tid; i < 512; i += 256) ((float*)sB)[i] = Ww1[i];
    if (tid < 8) { s3r[tid] = 0.0f; q3r[tid] = 0.0f; }

    const float invM = 1.0f / (float)MTOT;
    const float mean2 = ws[ST_OFF + 6 + lane] * invM;
    const float var2  = ws[ST_OFF + 70 + lane] * invM - mean2 * mean2;
    const float A2 = gw1[lane] * rsqrtf(var2 + EPSb);
    const float B2 = bw1_bn[lane] - mean2 * A2;
    float bw1r[8];
#pragma unroll
    for (int t = 0; t < 8; ++t) bw1r[t] = bw1[t];

    const u16* w0b = wsu + W0_US;
    float bs[8] = {0, 0, 0, 0, 0, 0, 0, 0};
    float bq2[8] = {0, 0, 0, 0, 0, 0, 0, 0};
    __syncthreads();

    for (int cc = 0; cc < 8; ++cc) {
        // phase 1: stream 32 pairs of w0 (bf16) -> bn2/relu -> LDS
#pragma unroll
        for (int nn = 0; nn < 2; ++nn) {
            const int n = gw * 16 + cc * 2 + nn;
#pragma unroll
            for (int j = 0; j < 16; ++j) {
                const float w0 = bf2f(w0b[(unsigned)(n * 16 + j) * 64u + lane]);
                sV[wid][nn * 16 + j][lane] = fmaxf(fmaf(w0, A2, B2), 0.0f);
            }
        }
        __syncthreads();
        // phase 2: [32,64] @ [64,8]
        const int pp = lane & 31;
        const int half = lane >> 5;
        float acc[8] = {0, 0, 0, 0, 0, 0, 0, 0};
#pragma unroll
        for (int k = 0; k < 32; ++k) {
            const int ci = half * 32 + k;
            const float v = sV[wid][pp][ci];
            const float4 bb0 = *(const float4*)&sB[ci][0];
            const float4 bb1 = *(const float4*)&sB[ci][4];
            acc[0] = fmaf(v, bb0.x, acc[0]); acc[1] = fmaf(v, bb0.y, acc[1]);
            acc[2] = fmaf(v, bb0.z, acc[2]); acc[3] = fmaf(v, bb0.w, acc[3]);
            acc[4] = fmaf(v, bb1.x, acc[4]); acc[5] = fmaf(v, bb1.y, acc[5]);
            acc[6] = fmaf(v, bb1.z, acc[6]); acc[7] = fmaf(v, bb1.w, acc[7]);
        }
#pragma unroll
        for (int t = 0; t < 8; ++t) acc[t] += __shfl_xor(acc[t], 32, 64);
        if (lane < 32) {
            const int pair = gw * 256 + cc * 32 + lane;
            float o[8];
#pragma unroll
            for (int t = 0; t < 8; ++t) {
                o[t] = acc[t] + bw1r[t];
                bs[t] += o[t];
                bq2[t] = fmaf(o[t], o[t], bq2[t]);
            }
            float4* dst = (float4*)(ws + W1P_OFF + (unsigned)pair * 8u);
            dst[0] = make_float4(o[0], o[1], o[2], o[3]);
            dst[1] = make_float4(o[4], o[5], o[6], o[7]);
        }
        __syncthreads();
    }
    if (lane < 32) {
#pragma unroll
        for (int t = 0; t < 8; ++t) { atomicAdd(&s3r[t], bs[t]); atomicAdd(&q3r[t], bq2[t]); }
    }
    __syncthreads();
    if (tid < 8) {
        atomicAdd(&ws[ST_OFF + 134 + tid], s3r[tid]);
        atomicAdd(&ws[ST_OFF + 142 + tid], q3r[tid]);
    }
}

// ---------------------------------------------------------------------------
// K4: bn3 -> relu -> @Ww2 -> softmax over 16 neighbors -> xv gather + aggregate
// ---------------------------------------------------------------------------
__global__ __launch_bounds__(256) void k4_final(
    const int* __restrict__ idx,
    const float* __restrict__ gp, const float* __restrict__ bp_bn,
    const float* __restrict__ Wp2, const float* __restrict__ bp2,
    const float* __restrict__ gw2, const float* __restrict__ bw2_bn,
    const float* __restrict__ Ww2, const float* __restrict__ bw2,
    const float* __restrict__ ws, float* __restrict__ out)
{
    const u16* wsu = (const u16*)ws;
    __shared__ float sv3[4][16][8];
    __shared__ float sw2[4][16][8];
    const int tid = threadIdx.x;
    const int lane = tid & 63;
    const int wid = tid >> 6;
    const int gw = blockIdx.x * 4 + wid;
    const int tt = lane & 7;

    const float invM = 1.0f / (float)MTOT;
    float A1[3], B1[3];
#pragma unroll
    for (int a = 0; a < 3; ++a) {
        const float mean = ws[ST_OFF + a] * invM;
        const float var  = ws[ST_OFF + 3 + a] * invM - mean * mean;
        const float sc = gp[a] * rsqrtf(var + EPSb);
        A1[a] = sc; B1[a] = bp_bn[a] - mean * sc;
    }
    const float mean3 = ws[ST_OFF + 134 + tt] * invM;
    const float var3  = ws[ST_OFF + 142 + tt] * invM - mean3 * mean3;
    const float A3 = gw2[tt] * rsqrtf(var3 + EPSb);
    const float B3 = bw2_bn[tt] - mean3 * A3;
    float ww2c[8];
#pragma unroll
    for (int u = 0; u < 8; ++u) ww2c[u] = Ww2[u * 8 + tt];
    const float bw2c = bw2[tt];
    const float wp20 = Wp2[lane], wp21 = Wp2[64 + lane], wp22 = Wp2[128 + lane];
    const float bp2c = bp2[lane];
    const float* T   = ws + T_OFF;
    const float* w1p = ws + W1P_OFF;
    const u16*  xvb  = wsu + XV_US;

    const int n0 = gw * 16;
    int   il = (lane < 16) ? idx[n0 * 16 + lane] : 0;
    float tl = (lane < 48) ? T[(unsigned)n0 * 48u + lane] : 0.0f;
    float v1 = w1p[(unsigned)n0 * 128u + lane];
    float v2 = w1p[(unsigned)n0 * 128u + 64u + lane];

    for (int it = 0; it < 16; ++it) {
        const int n = n0 + it;
        const int   ilc = il;
        const float tlc = tl;
        const float v1c = v1, v2c = v2;
        if (it < 15) {
            const int nx = n + 1;
            il = (lane < 16) ? idx[nx * 16 + lane] : 0;
            tl = (lane < 48) ? T[(unsigned)nx * 48u + lane] : 0.0f;
            v1 = w1p[(unsigned)nx * 128u + lane];
            v2 = w1p[(unsigned)nx * 128u + 64u + lane];
        }
        int nb[16];
#pragma unroll
        for (int j = 0; j < 16; ++j) nb[j] = __shfl(ilc, j, 64);
        u16 xvr[16];
#pragma unroll
        for (int j = 0; j < 16; ++j) xvr[j] = xvb[(unsigned)nb[j] * 64u + lane];

        sv3[wid][lane >> 3][tt]       = fmaxf(fmaf(v1c, A3, B3), 0.0f);
        sv3[wid][(lane >> 3) + 8][tt] = fmaxf(fmaf(v2c, A3, B3), 0.0f);
        __syncthreads();
        {
            const int j1 = lane >> 3;
            float a0 = bw2c, a1 = bw2c;
#pragma unroll
            for (int u = 0; u < 8; ++u) {
                a0 = fmaf(sv3[wid][j1][u], ww2c[u], a0);
                a1 = fmaf(sv3[wid][j1 + 8][u], ww2c[u], a1);
            }
            sw2[wid][j1][tt] = a0;
            sw2[wid][j1 + 8][tt] = a1;
        }
        __syncthreads();
        float mx = -1e30f;
#pragma unroll
        for (int j = 0; j < 16; ++j) mx = fmaxf(mx, sw2[wid][j][tt]);
        float e[16];
        float sum = 0.0f;
#pragma unroll
        for (int j = 0; j < 16; ++j) { e[j] = __expf(sw2[wid][j][tt] - mx); sum += e[j]; }
        const float inv = 1.0f / sum;
        float acc = 0.0f;
#pragma unroll
        for (int j = 0; j < 16; ++j) {
            float t0 = __shfl(tlc, 3 * j + 0, 64);
            float t1 = __shfl(tlc, 3 * j + 1, 64);
            float t2 = __shfl(tlc, 3 * j + 2, 64);
            t0 = fmaxf(fmaf(t0, A1[0], B1[0]), 0.0f);
            t1 = fmaxf(fmaf(t1, A1[1], B1[1]), 0.0f);
            t2 = fmaxf(fmaf(t2, A1[2], B1[2]), 0.0f);
            const float prc = bp2c + t0 * wp20 + t1 * wp21 + t2 * wp22;
            acc = fmaf(bf2f(xvr[j]) + prc, e[j] * inv, acc);
        }
        out[(unsigned)n * 64u + lane] = acc;
        __syncthreads();
    }
}

extern "C" void kernel_launch(void* const* d_in, const int* in_sizes, int n_in,
                              void* d_out, int out_size, void* d_ws, size_t ws_size,
                              hipStream_t stream)
{
    const float* p      = (const float*)d_in[0];
    const float* x      = (const float*)d_in[1];
    const int*   idx    = (const int*)d_in[2];
    const float* Wq     = (const float*)d_in[3];
    const float* bq     = (const float*)d_in[4];
    const float* Wk     = (const float*)d_in[5];
    const float* bk     = (const float*)d_in[6];
    const float* Wv     = (const float*)d_in[7];
    const float* bv     = (const float*)d_in[8];
    const float* Wp1    = (const float*)d_in[9];
    const float* bp1    = (const float*)d_in[10];
    const float* gp     = (const float*)d_in[11];
    const float* bp_bn  = (const float*)d_in[12];
    const float* Wp2    = (const float*)d_in[13];
    const float* bp2    = (const float*)d_in[14];
    const float* gw1    = (const float*)d_in[15];
    const float* bw1_bn = (const float*)d_in[16];
    const float* Ww1    = (const float*)d_in[17];
    const float* bw1    = (const float*)d_in[18];
    const float* gw2    = (const float*)d_in[19];
    const float* bw2_bn = (const float*)d_in[20];
    const float* Ww2    = (const float*)d_in[21];
    const float* bw2    = (const float*)d_in[22];
    float* ws  = (float*)d_ws;
    float* out = (float*)d_out;
    (void)in_sizes; (void)n_in; (void)out_size; (void)ws_size;

    // zero the stats accumulators
    hipMemsetAsync((char*)d_ws + (size_t)ST_OFF * 4, 0, 150 * sizeof(float), stream);

    k1_proj_bn1<<<1024, 256, 0, stream>>>(p, x, idx, Wq, bq, Wk, bk, Wv, bv, Wp1, bp1, ws);
    k2_bn2<<<1024, 256, 0, stream>>>(idx, gp, bp_bn, Wp2, bp2, ws);
    k3_w1_bn3<<<1024, 256, 0, stream>>>(gw1, bw1_bn, Ww1, bw1, ws);
    k4_final<<<1024, 256, 0, stream>>>(idx, gp, bp_bn, Wp2, bp2,
                                       gw2, bw2_bn, Ww2, bw2, ws, out);
}

// Round 3
// 370.948 us; speedup vs baseline: 1.5002x; 1.2403x over previous
//
#include <hip/hip_runtime.h>

typedef unsigned short u16;
typedef __attribute__((ext_vector_type(8))) short bf16x8;
typedef __attribute__((ext_vector_type(4))) float f32x4;

#define NPTS 65536
#define MTOT 1048576            // NPTS * NS
#define EPSb 1e-5f

// ---- workspace layout ----
// float-offsets from ws base:
#define XQ_OFF  0u              // f32 [NPTS,64]            16 MB
#define T_OFF   4194304u        // f32 [MTOT,3] raw bn1 in  12 MB
#define W1P_OFF 7340032u        // f32 [MTOT,8]             32 MB
#define ST_OFF  15728640u       // f32 [150] stats
// ushort-offsets from ws base:
#define XK_US   31457792u       // bf16 [NPTS,64]            8 MB
#define XV_US   35652096u       // bf16 [NPTS,64]            8 MB
#define W0_US   39846400u       // bf16 [MTOT,64]          128 MB

__device__ __forceinline__ float bf2f(u16 h) {
    return __uint_as_float(((unsigned)h) << 16);
}
__device__ __forceinline__ u16 f2bf(float f) {
    unsigned u = __float_as_uint(f);
    u += 0x7fffu + ((u >> 16) & 1u);      // round-to-nearest-even
    return (u16)(u >> 16);
}

// ---------------------------------------------------------------------------
// K1: xq/xk/xv projections via MFMA ([65536,64] @ [64,192] bf16) + BN1 stats.
// No LDS in the GEMM: 24 B-frags live in registers per wave (96 VGPRs).
// grid=512 blocks x 256 thr; each wave does 2 groups of 16 points.
// ---------------------------------------------------------------------------
__global__ __launch_bounds__(256) void k1_proj_bn1(
    const float* __restrict__ p, const float* __restrict__ x, const int* __restrict__ idx,
    const float* __restrict__ Wq, const float* __restrict__ bq,
    const float* __restrict__ Wk, const float* __restrict__ bk,
    const float* __restrict__ Wv, const float* __restrict__ bv,
    const float* __restrict__ Wp1, const float* __restrict__ bp1,
    float* __restrict__ ws)
{
    u16* wsu = (u16*)ws;
    __shared__ float sred[6];
    const int tid   = threadIdx.x;
    const int lane  = tid & 63;
    const int wid   = tid >> 6;
    const int col16 = lane & 15;
    const int quad  = lane >> 4;
    if (tid < 6) sred[tid] = 0.0f;
    __syncthreads();

    // ---- load B fragments: B[k=quad*8+j][n=16t+col16], bf16 ----
    const float* Wm[3] = { Wq, Wk, Wv };
    bf16x8 bf[3][4][2];
#pragma unroll
    for (int M = 0; M < 3; ++M)
#pragma unroll
        for (int t = 0; t < 4; ++t)
#pragma unroll
            for (int h = 0; h < 2; ++h) {
                bf16x8 tmp;
#pragma unroll
                for (int j = 0; j < 8; ++j)
                    tmp[j] = (short)f2bf(Wm[M][(h * 32 + quad * 8 + j) * 64 + t * 16 + col16]);
                bf[M][t][h] = tmp;
            }
    float bq_t[4], bk_t[4], bv_t[4];
#pragma unroll
    for (int t = 0; t < 4; ++t) {
        bq_t[t] = bq[t * 16 + col16];
        bk_t[t] = bk[t * 16 + col16];
        bv_t[t] = bv[t * 16 + col16];
    }

    float* xq  = ws + XQ_OFF;
    u16*  xkb  = wsu + XK_US;
    u16*  xvb  = wsu + XV_US;

    const int gw = blockIdx.x * 4 + wid;              // 0..2047
#pragma unroll
    for (int g = 0; g < 2; ++g) {
        const int n0 = (gw * 2 + g) * 16;
        // A frags: A[m=col16][k=quad*8+j (+32 for half 1)]
        const float* xrow = x + (unsigned)(n0 + col16) * 64u;
        const float4 fa0 = *(const float4*)&xrow[quad * 8];
        const float4 fa1 = *(const float4*)&xrow[quad * 8 + 4];
        const float4 fb0 = *(const float4*)&xrow[32 + quad * 8];
        const float4 fb1 = *(const float4*)&xrow[32 + quad * 8 + 4];
        bf16x8 a0, a1;
        a0[0] = (short)f2bf(fa0.x); a0[1] = (short)f2bf(fa0.y);
        a0[2] = (short)f2bf(fa0.z); a0[3] = (short)f2bf(fa0.w);
        a0[4] = (short)f2bf(fa1.x); a0[5] = (short)f2bf(fa1.y);
        a0[6] = (short)f2bf(fa1.z); a0[7] = (short)f2bf(fa1.w);
        a1[0] = (short)f2bf(fb0.x); a1[1] = (short)f2bf(fb0.y);
        a1[2] = (short)f2bf(fb0.z); a1[3] = (short)f2bf(fb0.w);
        a1[4] = (short)f2bf(fb1.x); a1[5] = (short)f2bf(fb1.y);
        a1[6] = (short)f2bf(fb1.z); a1[7] = (short)f2bf(fb1.w);

#pragma unroll
        for (int M = 0; M < 3; ++M) {
#pragma unroll
            for (int t = 0; t < 4; ++t) {
                f32x4 acc = {0.0f, 0.0f, 0.0f, 0.0f};
                acc = __builtin_amdgcn_mfma_f32_16x16x32_bf16(a0, bf[M][t][0], acc, 0, 0, 0);
                acc = __builtin_amdgcn_mfma_f32_16x16x32_bf16(a1, bf[M][t][1], acc, 0, 0, 0);
#pragma unroll
                for (int r = 0; r < 4; ++r) {
                    const unsigned row = (unsigned)(n0 + quad * 4 + r);
                    const unsigned o   = row * 64u + (unsigned)(t * 16 + col16);
                    if (M == 0)      xq[o]  = acc[r] + bq_t[t];
                    else if (M == 1) xkb[o] = f2bf(acc[r] + bk_t[t]);
                    else             xvb[o] = f2bf(acc[r] + bv_t[t]);
                }
            }
        }
    }

    // ---- BN1 stats + store raw T: this block's 2048 pairs ----
    const int base = blockIdx.x * 128;
    const float w00 = Wp1[0], w01 = Wp1[1], w02 = Wp1[2];
    const float w10 = Wp1[3], w11 = Wp1[4], w12 = Wp1[5];
    const float w20 = Wp1[6], w21 = Wp1[7], w22 = Wp1[8];
    const float c0 = bp1[0], c1 = bp1[1], c2 = bp1[2];
    float s0 = 0, s1 = 0, s2 = 0, q0 = 0, q1 = 0, q2 = 0;
#pragma unroll
    for (int m = 0; m < 8; ++m) {
        const int pl = tid + m * 256;            // 0..2047
        const int n  = base + (pl >> 4);
        const unsigned gpair = (unsigned)(base * 16 + pl);
        const int nb = idx[gpair];
        const float r0 = p[nb * 3 + 0] - p[n * 3 + 0];
        const float r1 = p[nb * 3 + 1] - p[n * 3 + 1];
        const float r2 = p[nb * 3 + 2] - p[n * 3 + 2];
        const float t0 = c0 + r0 * w00 + r1 * w10 + r2 * w20;
        const float t1 = c1 + r0 * w01 + r1 * w11 + r2 * w21;
        const float t2 = c2 + r0 * w02 + r1 * w12 + r2 * w22;
        ws[T_OFF + gpair * 3u + 0u] = t0;
        ws[T_OFF + gpair * 3u + 1u] = t1;
        ws[T_OFF + gpair * 3u + 2u] = t2;
        s0 += t0; s1 += t1; s2 += t2;
        q0 += t0 * t0; q1 += t1 * t1; q2 += t2 * t2;
    }
    atomicAdd(&sred[0], s0); atomicAdd(&sred[1], s1); atomicAdd(&sred[2], s2);
    atomicAdd(&sred[3], q0); atomicAdd(&sred[4], q1); atomicAdd(&sred[5], q2);
    __syncthreads();
    if (tid < 6) atomicAdd(&ws[ST_OFF + tid], sred[tid]);
}

// ---------------------------------------------------------------------------
// K2: w0 = xk[idx] - xq + pr ; store w0 bf16 ; BN2 stats
// ---------------------------------------------------------------------------
__global__ __launch_bounds__(256) void k2_bn2(
    const int* __restrict__ idx,
    const float* __restrict__ gp, const float* __restrict__ bp_bn,
    const float* __restrict__ Wp2, const float* __restrict__ bp2,
    float* __restrict__ ws)
{
    u16* wsu = (u16*)ws;
    __shared__ float ss[64], sq[64];
    const int tid = threadIdx.x;
    const int lane = tid & 63;
    const int gw = blockIdx.x * 4 + (tid >> 6);
    if (tid < 64) { ss[tid] = 0.0f; sq[tid] = 0.0f; }

    const float invM = 1.0f / (float)MTOT;
    float A1[3], B1[3];
#pragma unroll
    for (int a = 0; a < 3; ++a) {
        const float mean = ws[ST_OFF + a] * invM;
        const float var  = ws[ST_OFF + 3 + a] * invM - mean * mean;
        const float sc = gp[a] * rsqrtf(var + EPSb);
        A1[a] = sc; B1[a] = bp_bn[a] - mean * sc;
    }
    const float wp20 = Wp2[lane], wp21 = Wp2[64 + lane], wp22 = Wp2[128 + lane];
    const float bp2c = bp2[lane];
    const float* xq  = ws + XQ_OFF;
    const float* T   = ws + T_OFF;
    const u16*  xkb  = wsu + XK_US;
    u16*        w0b  = wsu + W0_US;

    float s = 0.0f, q = 0.0f;
    const int n0 = gw * 16;
    int   il  = (lane < 16) ? idx[n0 * 16 + lane] : 0;
    float tl  = (lane < 48) ? T[(unsigned)n0 * 48u + lane] : 0.0f;
    float xqc = xq[(unsigned)n0 * 64u + lane];

    for (int nn = 0; nn < 16; ++nn) {
        const int n = n0 + nn;
        const int   ilc = il;
        const float tlc = tl;
        const float xqq = xqc;
        if (nn < 15) {
            const int nx = n + 1;
            il  = (lane < 16) ? idx[nx * 16 + lane] : 0;
            tl  = (lane < 48) ? T[(unsigned)nx * 48u + lane] : 0.0f;
            xqc = xq[(unsigned)nx * 64u + lane];
        }
        int nb[16];
#pragma unroll
        for (int j = 0; j < 16; ++j) nb[j] = __shfl(ilc, j, 64);
        u16 kr[16];
#pragma unroll
        for (int j = 0; j < 16; ++j) kr[j] = xkb[(unsigned)nb[j] * 64u + lane];
#pragma unroll
        for (int j = 0; j < 16; ++j) {
            float t0 = __shfl(tlc, 3 * j + 0, 64);
            float t1 = __shfl(tlc, 3 * j + 1, 64);
            float t2 = __shfl(tlc, 3 * j + 2, 64);
            t0 = fmaxf(fmaf(t0, A1[0], B1[0]), 0.0f);
            t1 = fmaxf(fmaf(t1, A1[1], B1[1]), 0.0f);
            t2 = fmaxf(fmaf(t2, A1[2], B1[2]), 0.0f);
            const float prc = bp2c + t0 * wp20 + t1 * wp21 + t2 * wp22;
            const float w0 = bf2f(kr[j]) - xqq + prc;
            s += w0; q = fmaf(w0, w0, q);
            w0b[(unsigned)(n * 16 + j) * 64u + lane] = f2bf(w0);
        }
    }
    __syncthreads();
    atomicAdd(&ss[lane], s); atomicAdd(&sq[lane], q);
    __syncthreads();
    if (tid < 64) {
        atomicAdd(&ws[ST_OFF + 6 + tid], ss[tid]);
        atomicAdd(&ws[ST_OFF + 70 + tid], sq[tid]);
    }
}

// ---------------------------------------------------------------------------
// K3: w1' = relu(bn2(w0)) @ Ww1 + bw1 (streaming read of stored w0) + BN3 stats
// ---------------------------------------------------------------------------
__global__ __launch_bounds__(256) void k3_w1_bn3(
    const float* __restrict__ gw1, const float* __restrict__ bw1_bn,
    const float* __restrict__ Ww1, const float* __restrict__ bw1,
    float* __restrict__ ws)
{
    u16* wsu = (u16*)ws;
    __shared__ __align__(16) float sV[4][32][65];
    __shared__ __align__(16) float sB[64][8];
    __shared__ float s3r[8], q3r[8];
    const int tid = threadIdx.x;
    const int lane = tid & 63;
    const int wid = tid >> 6;
    const int gw = blockIdx.x * 4 + wid;
    for (int i = tid; i < 512; i += 256) ((float*)sB)[i] = Ww1[i];
    if (tid < 8) { s3r[tid] = 0.0f; q3r[tid] = 0.0f; }

    const float invM = 1.0f / (float)MTOT;
    const float mean2 = ws[ST_OFF + 6 + lane] * invM;
    const float var2  = ws[ST_OFF + 70 + lane] * invM - mean2 * mean2;
    const float A2 = gw1[lane] * rsqrtf(var2 + EPSb);
    const float B2 = bw1_bn[lane] - mean2 * A2;
    float bw1r[8];
#pragma unroll
    for (int t = 0; t < 8; ++t) bw1r[t] = bw1[t];

    const u16* w0b = wsu + W0_US;
    float bs[8] = {0, 0, 0, 0, 0, 0, 0, 0};
    float bq2[8] = {0, 0, 0, 0, 0, 0, 0, 0};
    __syncthreads();

    for (int cc = 0; cc < 8; ++cc) {
#pragma unroll
        for (int nn = 0; nn < 2; ++nn) {
            const int n = gw * 16 + cc * 2 + nn;
#pragma unroll
            for (int j = 0; j < 16; ++j) {
                const float w0 = bf2f(w0b[(unsigned)(n * 16 + j) * 64u + lane]);
                sV[wid][nn * 16 + j][lane] = fmaxf(fmaf(w0, A2, B2), 0.0f);
            }
        }
        __syncthreads();
        const int pp = lane & 31;
        const int half = lane >> 5;
        float acc[8] = {0, 0, 0, 0, 0, 0, 0, 0};
#pragma unroll
        for (int k = 0; k < 32; ++k) {
            const int ci = half * 32 + k;
            const float v = sV[wid][pp][ci];
            const float4 bb0 = *(const float4*)&sB[ci][0];
            const float4 bb1 = *(const float4*)&sB[ci][4];
            acc[0] = fmaf(v, bb0.x, acc[0]); acc[1] = fmaf(v, bb0.y, acc[1]);
            acc[2] = fmaf(v, bb0.z, acc[2]); acc[3] = fmaf(v, bb0.w, acc[3]);
            acc[4] = fmaf(v, bb1.x, acc[4]); acc[5] = fmaf(v, bb1.y, acc[5]);
            acc[6] = fmaf(v, bb1.z, acc[6]); acc[7] = fmaf(v, bb1.w, acc[7]);
        }
#pragma unroll
        for (int t = 0; t < 8; ++t) acc[t] += __shfl_xor(acc[t], 32, 64);
        if (lane < 32) {
            const int pair = gw * 256 + cc * 32 + lane;
            float o[8];
#pragma unroll
            for (int t = 0; t < 8; ++t) {
                o[t] = acc[t] + bw1r[t];
                bs[t] += o[t];
                bq2[t] = fmaf(o[t], o[t], bq2[t]);
            }
            float4* dst = (float4*)(ws + W1P_OFF + (unsigned)pair * 8u);
            dst[0] = make_float4(o[0], o[1], o[2], o[3]);
            dst[1] = make_float4(o[4], o[5], o[6], o[7]);
        }
        __syncthreads();
    }
    if (lane < 32) {
#pragma unroll
        for (int t = 0; t < 8; ++t) { atomicAdd(&s3r[t], bs[t]); atomicAdd(&q3r[t], bq2[t]); }
    }
    __syncthreads();
    if (tid < 8) {
        atomicAdd(&ws[ST_OFF + 134 + tid], s3r[tid]);
        atomicAdd(&ws[ST_OFF + 142 + tid], q3r[tid]);
    }
}

// ---------------------------------------------------------------------------
// K4: bn3 -> relu -> @Ww2 -> softmax over 16 neighbors -> xv gather + aggregate
// ---------------------------------------------------------------------------
__global__ __launch_bounds__(256) void k4_final(
    const int* __restrict__ idx,
    const float* __restrict__ gp, const float* __restrict__ bp_bn,
    const float* __restrict__ Wp2, const float* __restrict__ bp2,
    const float* __restrict__ gw2, const float* __restrict__ bw2_bn,
    const float* __restrict__ Ww2, const float* __restrict__ bw2,
    const float* __restrict__ ws, float* __restrict__ out)
{
    const u16* wsu = (const u16*)ws;
    __shared__ float sv3[4][16][8];
    __shared__ float sw2[4][16][8];
    const int tid = threadIdx.x;
    const int lane = tid & 63;
    const int wid = tid >> 6;
    const int gw = blockIdx.x * 4 + wid;
    const int tt = lane & 7;

    const float invM = 1.0f / (float)MTOT;
    float A1[3], B1[3];
#pragma unroll
    for (int a = 0; a < 3; ++a) {
        const float mean = ws[ST_OFF + a] * invM;
        const float var  = ws[ST_OFF + 3 + a] * invM - mean * mean;
        const float sc = gp[a] * rsqrtf(var + EPSb);
        A1[a] = sc; B1[a] = bp_bn[a] - mean * sc;
    }
    const float mean3 = ws[ST_OFF + 134 + tt] * invM;
    const float var3  = ws[ST_OFF + 142 + tt] * invM - mean3 * mean3;
    const float A3 = gw2[tt] * rsqrtf(var3 + EPSb);
    const float B3 = bw2_bn[tt] - mean3 * A3;
    float ww2c[8];
#pragma unroll
    for (int u = 0; u < 8; ++u) ww2c[u] = Ww2[u * 8 + tt];
    const float bw2c = bw2[tt];
    const float wp20 = Wp2[lane], wp21 = Wp2[64 + lane], wp22 = Wp2[128 + lane];
    const float bp2c = bp2[lane];
    const float* T   = ws + T_OFF;
    const float* w1p = ws + W1P_OFF;
    const u16*  xvb  = wsu + XV_US;

    const int n0 = gw * 16;
    int   il = (lane < 16) ? idx[n0 * 16 + lane] : 0;
    float tl = (lane < 48) ? T[(unsigned)n0 * 48u + lane] : 0.0f;
    float v1 = w1p[(unsigned)n0 * 128u + lane];
    float v2 = w1p[(unsigned)n0 * 128u + 64u + lane];

    for (int it = 0; it < 16; ++it) {
        const int n = n0 + it;
        const int   ilc = il;
        const float tlc = tl;
        const float v1c = v1, v2c = v2;
        if (it < 15) {
            const int nx = n + 1;
            il = (lane < 16) ? idx[nx * 16 + lane] : 0;
            tl = (lane < 48) ? T[(unsigned)nx * 48u + lane] : 0.0f;
            v1 = w1p[(unsigned)nx * 128u + lane];
            v2 = w1p[(unsigned)nx * 128u + 64u + lane];
        }
        int nb[16];
#pragma unroll
        for (int j = 0; j < 16; ++j) nb[j] = __shfl(ilc, j, 64);
        u16 xvr[16];
#pragma unroll
        for (int j = 0; j < 16; ++j) xvr[j] = xvb[(unsigned)nb[j] * 64u + lane];

        sv3[wid][lane >> 3][tt]       = fmaxf(fmaf(v1c, A3, B3), 0.0f);
        sv3[wid][(lane >> 3) + 8][tt] = fmaxf(fmaf(v2c, A3, B3), 0.0f);
        __syncthreads();
        {
            const int j1 = lane >> 3;
            float a0 = bw2c, a1 = bw2c;
#pragma unroll
            for (int u = 0; u < 8; ++u) {
                a0 = fmaf(sv3[wid][j1][u], ww2c[u], a0);
                a1 = fmaf(sv3[wid][j1 + 8][u], ww2c[u], a1);
            }
            sw2[wid][j1][tt] = a0;
            sw2[wid][j1 + 8][tt] = a1;
        }
        __syncthreads();
        float mx = -1e30f;
#pragma unroll
        for (int j = 0; j < 16; ++j) mx = fmaxf(mx, sw2[wid][j][tt]);
        float e[16];
        float sum = 0.0f;
#pragma unroll
        for (int j = 0; j < 16; ++j) { e[j] = __expf(sw2[wid][j][tt] - mx); sum += e[j]; }
        const float inv = 1.0f / sum;
        float acc = 0.0f;
#pragma unroll
        for (int j = 0; j < 16; ++j) {
            float t0 = __shfl(tlc, 3 * j + 0, 64);
            float t1 = __shfl(tlc, 3 * j + 1, 64);
            float t2 = __shfl(tlc, 3 * j + 2, 64);
            t0 = fmaxf(fmaf(t0, A1[0], B1[0]), 0.0f);
            t1 = fmaxf(fmaf(t1, A1[1], B1[1]), 0.0f);
            t2 = fmaxf(fmaf(t2, A1[2], B1[2]), 0.0f);
            const float prc = bp2c + t0 * wp20 + t1 * wp21 + t2 * wp22;
            acc = fmaf(bf2f(xvr[j]) + prc, e[j] * inv, acc);
        }
        out[(unsigned)n * 64u + lane] = acc;
        __syncthreads();
    }
}

extern "C" void kernel_launch(void* const* d_in, const int* in_sizes, int n_in,
                              void* d_out, int out_size, void* d_ws, size_t ws_size,
                              hipStream_t stream)
{
    const float* p      = (const float*)d_in[0];
    const float* x      = (const float*)d_in[1];
    const int*   idx    = (const int*)d_in[2];
    const float* Wq     = (const float*)d_in[3];
    const float* bq     = (const float*)d_in[4];
    const float* Wk     = (const float*)d_in[5];
    const float* bk     = (const float*)d_in[6];
    const float* Wv     = (const float*)d_in[7];
    const float* bv     = (const float*)d_in[8];
    const float* Wp1    = (const float*)d_in[9];
    const float* bp1    = (const float*)d_in[10];
    const float* gp     = (const float*)d_in[11];
    const float* bp_bn  = (const float*)d_in[12];
    const float* Wp2    = (const float*)d_in[13];
    const float* bp2    = (const float*)d_in[14];
    const float* gw1    = (const float*)d_in[15];
    const float* bw1_bn = (const float*)d_in[16];
    const float* Ww1    = (const float*)d_in[17];
    const float* bw1    = (const float*)d_in[18];
    const float* gw2    = (const float*)d_in[19];
    const float* bw2_bn = (const float*)d_in[20];
    const float* Ww2    = (const float*)d_in[21];
    const float* bw2    = (const float*)d_in[22];
    float* ws  = (float*)d_ws;
    float* out = (float*)d_out;
    (void)in_sizes; (void)n_in; (void)out_size; (void)ws_size;

    hipMemsetAsync((char*)d_ws + (size_t)ST_OFF * 4, 0, 150 * sizeof(float), stream);

    k1_proj_bn1<<<512, 256, 0, stream>>>(p, x, idx, Wq, bq, Wk, bk, Wv, bv, Wp1, bp1, ws);
    k2_bn2<<<1024, 256, 0, stream>>>(idx, gp, bp_bn, Wp2, bp2, ws);
    k3_w1_bn3<<<1024, 256, 0, stream>>>(gw1, bw1_bn, Ww1, bw1, ws);
    k4_final<<<1024, 256, 0, stream>>>(idx, gp, bp_bn, Wp2, bp2,
                                       gw2, bw2_bn, Ww2, bw2, ws, out);
}

// Round 4
// 326.108 us; speedup vs baseline: 1.7065x; 1.1375x over previous
//
#include <hip/hip_runtime.h>

typedef unsigned short u16;
typedef __attribute__((ext_vector_type(8))) short bf16x8;
typedef __attribute__((ext_vector_type(8))) unsigned short u16x8;
typedef __attribute__((ext_vector_type(4))) float f32x4;

#define NPTS 65536
#define MTOT 1048576            // NPTS * NS
#define EPSb 1e-5f

// ---- workspace layout ----
// float-offsets from ws base:
#define XQ_OFF  0u              // f32 [NPTS,64]            16 MB
#define T_OFF   4194304u        // f32 [MTOT,3] raw bn1 in  12 MB
#define W1P_OFF 7340032u        // f32 [MTOT,8]             32 MB
#define ST_OFF  15728640u       // f32 [150] stats
// ushort-offsets from ws base:
#define XK_US   31457792u       // bf16 [NPTS,64]            8 MB
#define XV_US   35652096u       // bf16 [NPTS,64]            8 MB
#define W0_US   39846400u       // bf16 [MTOT,64]          128 MB

__device__ __forceinline__ float bf2f(u16 h) {
    return __uint_as_float(((unsigned)h) << 16);
}
__device__ __forceinline__ u16 f2bf(float f) {
    unsigned u = __float_as_uint(f);
    u += 0x7fffu + ((u >> 16) & 1u);      // round-to-nearest-even
    return (u16)(u >> 16);
}

// ---------------------------------------------------------------------------
// K1: xq/xk/xv projections via MFMA ([65536,64] @ [64,192] bf16) + BN1 stats.
// ---------------------------------------------------------------------------
__global__ __launch_bounds__(256) void k1_proj_bn1(
    const float* __restrict__ p, const float* __restrict__ x, const int* __restrict__ idx,
    const float* __restrict__ Wq, const float* __restrict__ bq,
    const float* __restrict__ Wk, const float* __restrict__ bk,
    const float* __restrict__ Wv, const float* __restrict__ bv,
    const float* __restrict__ Wp1, const float* __restrict__ bp1,
    float* __restrict__ ws)
{
    u16* wsu = (u16*)ws;
    __shared__ float sred[6];
    const int tid   = threadIdx.x;
    const int lane  = tid & 63;
    const int wid   = tid >> 6;
    const int col16 = lane & 15;
    const int quad  = lane >> 4;
    if (tid < 6) sred[tid] = 0.0f;
    __syncthreads();

    // ---- load B fragments: B[k=quad*8+j][n=16t+col16], bf16 ----
    const float* Wm[3] = { Wq, Wk, Wv };
    bf16x8 bf[3][4][2];
#pragma unroll
    for (int M = 0; M < 3; ++M)
#pragma unroll
        for (int t = 0; t < 4; ++t)
#pragma unroll
            for (int h = 0; h < 2; ++h) {
                bf16x8 tmp;
#pragma unroll
                for (int j = 0; j < 8; ++j)
                    tmp[j] = (short)f2bf(Wm[M][(h * 32 + quad * 8 + j) * 64 + t * 16 + col16]);
                bf[M][t][h] = tmp;
            }
    float bq_t[4], bk_t[4], bv_t[4];
#pragma unroll
    for (int t = 0; t < 4; ++t) {
        bq_t[t] = bq[t * 16 + col16];
        bk_t[t] = bk[t * 16 + col16];
        bv_t[t] = bv[t * 16 + col16];
    }

    float* xq  = ws + XQ_OFF;
    u16*  xkb  = wsu + XK_US;
    u16*  xvb  = wsu + XV_US;

    const int gw = blockIdx.x * 4 + wid;              // 0..2047
#pragma unroll
    for (int g = 0; g < 2; ++g) {
        const int n0 = (gw * 2 + g) * 16;
        const float* xrow = x + (unsigned)(n0 + col16) * 64u;
        const float4 fa0 = *(const float4*)&xrow[quad * 8];
        const float4 fa1 = *(const float4*)&xrow[quad * 8 + 4];
        const float4 fb0 = *(const float4*)&xrow[32 + quad * 8];
        const float4 fb1 = *(const float4*)&xrow[32 + quad * 8 + 4];
        bf16x8 a0, a1;
        a0[0] = (short)f2bf(fa0.x); a0[1] = (short)f2bf(fa0.y);
        a0[2] = (short)f2bf(fa0.z); a0[3] = (short)f2bf(fa0.w);
        a0[4] = (short)f2bf(fa1.x); a0[5] = (short)f2bf(fa1.y);
        a0[6] = (short)f2bf(fa1.z); a0[7] = (short)f2bf(fa1.w);
        a1[0] = (short)f2bf(fb0.x); a1[1] = (short)f2bf(fb0.y);
        a1[2] = (short)f2bf(fb0.z); a1[3] = (short)f2bf(fb0.w);
        a1[4] = (short)f2bf(fb1.x); a1[5] = (short)f2bf(fb1.y);
        a1[6] = (short)f2bf(fb1.z); a1[7] = (short)f2bf(fb1.w);

#pragma unroll
        for (int M = 0; M < 3; ++M) {
#pragma unroll
            for (int t = 0; t < 4; ++t) {
                f32x4 acc = {0.0f, 0.0f, 0.0f, 0.0f};
                acc = __builtin_amdgcn_mfma_f32_16x16x32_bf16(a0, bf[M][t][0], acc, 0, 0, 0);
                acc = __builtin_amdgcn_mfma_f32_16x16x32_bf16(a1, bf[M][t][1], acc, 0, 0, 0);
#pragma unroll
                for (int r = 0; r < 4; ++r) {
                    const unsigned row = (unsigned)(n0 + quad * 4 + r);
                    const unsigned o   = row * 64u + (unsigned)(t * 16 + col16);
                    if (M == 0)      xq[o]  = acc[r] + bq_t[t];
                    else if (M == 1) xkb[o] = f2bf(acc[r] + bk_t[t]);
                    else             xvb[o] = f2bf(acc[r] + bv_t[t]);
                }
            }
        }
    }

    // ---- BN1 stats + store raw T: this block's 2048 pairs ----
    const int base = blockIdx.x * 128;
    const float w00 = Wp1[0], w01 = Wp1[1], w02 = Wp1[2];
    const float w10 = Wp1[3], w11 = Wp1[4], w12 = Wp1[5];
    const float w20 = Wp1[6], w21 = Wp1[7], w22 = Wp1[8];
    const float c0 = bp1[0], c1 = bp1[1], c2 = bp1[2];
    float s0 = 0, s1 = 0, s2 = 0, q0 = 0, q1 = 0, q2 = 0;
#pragma unroll
    for (int m = 0; m < 8; ++m) {
        const int pl = tid + m * 256;            // 0..2047
        const int n  = base + (pl >> 4);
        const unsigned gpair = (unsigned)(base * 16 + pl);
        const int nb = idx[gpair];
        const float r0 = p[nb * 3 + 0] - p[n * 3 + 0];
        const float r1 = p[nb * 3 + 1] - p[n * 3 + 1];
        const float r2 = p[nb * 3 + 2] - p[n * 3 + 2];
        const float t0 = c0 + r0 * w00 + r1 * w10 + r2 * w20;
        const float t1 = c1 + r0 * w01 + r1 * w11 + r2 * w21;
        const float t2 = c2 + r0 * w02 + r1 * w12 + r2 * w22;
        ws[T_OFF + gpair * 3u + 0u] = t0;
        ws[T_OFF + gpair * 3u + 1u] = t1;
        ws[T_OFF + gpair * 3u + 2u] = t2;
        s0 += t0; s1 += t1; s2 += t2;
        q0 += t0 * t0; q1 += t1 * t1; q2 += t2 * t2;
    }
    atomicAdd(&sred[0], s0); atomicAdd(&sred[1], s1); atomicAdd(&sred[2], s2);
    atomicAdd(&sred[3], q0); atomicAdd(&sred[4], q1); atomicAdd(&sred[5], q2);
    __syncthreads();
    if (tid < 6) atomicAdd(&ws[ST_OFF + tid], sred[tid]);
}

// ---------------------------------------------------------------------------
// K2: w0 = xk[idx] - xq + pr ; store w0 bf16 ; BN2 stats
// ---------------------------------------------------------------------------
__global__ __launch_bounds__(256) void k2_bn2(
    const int* __restrict__ idx,
    const float* __restrict__ gp, const float* __restrict__ bp_bn,
    const float* __restrict__ Wp2, const float* __restrict__ bp2,
    float* __restrict__ ws)
{
    u16* wsu = (u16*)ws;
    __shared__ float ss[64], sq[64];
    const int tid = threadIdx.x;
    const int lane = tid & 63;
    const int gw = blockIdx.x * 4 + (tid >> 6);
    if (tid < 64) { ss[tid] = 0.0f; sq[tid] = 0.0f; }

    const float invM = 1.0f / (float)MTOT;
    float A1[3], B1[3];
#pragma unroll
    for (int a = 0; a < 3; ++a) {
        const float mean = ws[ST_OFF + a] * invM;
        const float var  = ws[ST_OFF + 3 + a] * invM - mean * mean;
        const float sc = gp[a] * rsqrtf(var + EPSb);
        A1[a] = sc; B1[a] = bp_bn[a] - mean * sc;
    }
    const float wp20 = Wp2[lane], wp21 = Wp2[64 + lane], wp22 = Wp2[128 + lane];
    const float bp2c = bp2[lane];
    const float* xq  = ws + XQ_OFF;
    const float* T   = ws + T_OFF;
    const u16*  xkb  = wsu + XK_US;
    u16*        w0b  = wsu + W0_US;

    float s = 0.0f, q = 0.0f;
    const int n0 = gw * 16;
    int   il  = (lane < 16) ? idx[n0 * 16 + lane] : 0;
    float tl  = (lane < 48) ? T[(unsigned)n0 * 48u + lane] : 0.0f;
    float xqc = xq[(unsigned)n0 * 64u + lane];

    for (int nn = 0; nn < 16; ++nn) {
        const int n = n0 + nn;
        const int   ilc = il;
        const float tlc = tl;
        const float xqq = xqc;
        if (nn < 15) {
            const int nx = n + 1;
            il  = (lane < 16) ? idx[nx * 16 + lane] : 0;
            tl  = (lane < 48) ? T[(unsigned)nx * 48u + lane] : 0.0f;
            xqc = xq[(unsigned)nx * 64u + lane];
        }
        int nb[16];
#pragma unroll
        for (int j = 0; j < 16; ++j) nb[j] = __shfl(ilc, j, 64);
        u16 kr[16];
#pragma unroll
        for (int j = 0; j < 16; ++j) kr[j] = xkb[(unsigned)nb[j] * 64u + lane];
#pragma unroll
        for (int j = 0; j < 16; ++j) {
            float t0 = __shfl(tlc, 3 * j + 0, 64);
            float t1 = __shfl(tlc, 3 * j + 1, 64);
            float t2 = __shfl(tlc, 3 * j + 2, 64);
            t0 = fmaxf(fmaf(t0, A1[0], B1[0]), 0.0f);
            t1 = fmaxf(fmaf(t1, A1[1], B1[1]), 0.0f);
            t2 = fmaxf(fmaf(t2, A1[2], B1[2]), 0.0f);
            const float prc = bp2c + t0 * wp20 + t1 * wp21 + t2 * wp22;
            const float w0 = bf2f(kr[j]) - xqq + prc;
            s += w0; q = fmaf(w0, w0, q);
            w0b[(unsigned)(n * 16 + j) * 64u + lane] = f2bf(w0);
        }
    }
    __syncthreads();
    atomicAdd(&ss[lane], s); atomicAdd(&sq[lane], q);
    __syncthreads();
    if (tid < 64) {
        atomicAdd(&ws[ST_OFF + 6 + tid], ss[tid]);
        atomicAdd(&ws[ST_OFF + 70 + tid], sq[tid]);
    }
}

// ---------------------------------------------------------------------------
// K3: w1' = relu(bn2(w0)) @ Ww1 + bw1 via MFMA, barrier-free, no LDS staging.
// A = w0 [pair][64ch] loaded as ushort8 directly in A-fragment order.
// B = Ww1 zero-padded to 16 cols. grid 1024x256: wave = 16 tiles of 16 pairs.
// ---------------------------------------------------------------------------
__global__ __launch_bounds__(256) void k3_w1_bn3(
    const float* __restrict__ gw1, const float* __restrict__ bw1_bn,
    const float* __restrict__ Ww1, const float* __restrict__ bw1,
    float* __restrict__ ws)
{
    u16* wsu = (u16*)ws;
    __shared__ float s3r[8], q3r[8];
    const int tid   = threadIdx.x;
    const int lane  = tid & 63;
    const int wid   = tid >> 6;
    const int col16 = lane & 15;
    const int quad  = lane >> 4;
    if (tid < 8) { s3r[tid] = 0.0f; q3r[tid] = 0.0f; }
    __syncthreads();

    const float invM = 1.0f / (float)MTOT;
    // per-lane bn2 affine for its 16 channels (quad*8+j and +32)
    float A2q[8], B2q[8], A2h[8], B2h[8];
#pragma unroll
    for (int j = 0; j < 8; ++j) {
        {
            const int c = quad * 8 + j;
            const float mean = ws[ST_OFF + 6 + c] * invM;
            const float var  = ws[ST_OFF + 70 + c] * invM - mean * mean;
            A2q[j] = gw1[c] * rsqrtf(var + EPSb);
            B2q[j] = bw1_bn[c] - mean * A2q[j];
        }
        {
            const int c = 32 + quad * 8 + j;
            const float mean = ws[ST_OFF + 6 + c] * invM;
            const float var  = ws[ST_OFF + 70 + c] * invM - mean * mean;
            A2h[j] = gw1[c] * rsqrtf(var + EPSb);
            B2h[j] = bw1_bn[c] - mean * A2h[j];
        }
    }
    // B fragments: B[k=quad*8+j][n=col16], cols 8..15 zero
    bf16x8 b0, b1;
#pragma unroll
    for (int j = 0; j < 8; ++j) {
        const int k0 = quad * 8 + j;
        b0[j] = (col16 < 8) ? (short)f2bf(Ww1[k0 * 8 + col16]) : (short)0;
        b1[j] = (col16 < 8) ? (short)f2bf(Ww1[(k0 + 32) * 8 + col16]) : (short)0;
    }
    const float bw1c = (col16 < 8) ? bw1[col16] : 0.0f;

    const u16* w0b = wsu + W0_US;
    float* w1p = ws + W1P_OFF;
    const int wgid = blockIdx.x * 4 + wid;            // 0..4095
    float bs = 0.0f, bq2 = 0.0f;

#pragma unroll 2
    for (int t = 0; t < 16; ++t) {
        const int pair0 = (wgid * 16 + t) * 16;
        const u16* rowp = w0b + (unsigned)(pair0 + col16) * 64u;
        const u16x8 r0 = *(const u16x8*)(rowp + quad * 8);
        const u16x8 r1 = *(const u16x8*)(rowp + 32 + quad * 8);
        bf16x8 a0, a1;
#pragma unroll
        for (int j = 0; j < 8; ++j) {
            float f0 = fmaxf(fmaf(bf2f(r0[j]), A2q[j], B2q[j]), 0.0f);
            float f1 = fmaxf(fmaf(bf2f(r1[j]), A2h[j], B2h[j]), 0.0f);
            a0[j] = (short)f2bf(f0);
            a1[j] = (short)f2bf(f1);
        }
        f32x4 acc = {0.0f, 0.0f, 0.0f, 0.0f};
        acc = __builtin_amdgcn_mfma_f32_16x16x32_bf16(a0, b0, acc, 0, 0, 0);
        acc = __builtin_amdgcn_mfma_f32_16x16x32_bf16(a1, b1, acc, 0, 0, 0);
        if (col16 < 8) {
#pragma unroll
            for (int r = 0; r < 4; ++r) {
                const float o = acc[r] + bw1c;
                w1p[(unsigned)(pair0 + quad * 4 + r) * 8u + (unsigned)col16] = o;
                bs += o;
                bq2 = fmaf(o, o, bq2);
            }
        }
    }
    if (col16 < 8) {
        atomicAdd(&s3r[col16], bs);
        atomicAdd(&q3r[col16], bq2);
    }
    __syncthreads();
    if (tid < 8) {
        atomicAdd(&ws[ST_OFF + 134 + tid], s3r[tid]);
        atomicAdd(&ws[ST_OFF + 142 + tid], q3r[tid]);
    }
}

// ---------------------------------------------------------------------------
// K4: bn3 -> relu -> @Ww2 -> softmax over 16 neighbors -> xv gather + aggregate
// ---------------------------------------------------------------------------
__global__ __launch_bounds__(256) void k4_final(
    const int* __restrict__ idx,
    const float* __restrict__ gp, const float* __restrict__ bp_bn,
    const float* __restrict__ Wp2, const float* __restrict__ bp2,
    const float* __restrict__ gw2, const float* __restrict__ bw2_bn,
    const float* __restrict__ Ww2, const float* __restrict__ bw2,
    const float* __restrict__ ws, float* __restrict__ out)
{
    const u16* wsu = (const u16*)ws;
    __shared__ float sv3[4][16][8];
    __shared__ float sw2[4][16][8];
    const int tid = threadIdx.x;
    const int lane = tid & 63;
    const int wid = tid >> 6;
    const int gw = blockIdx.x * 4 + wid;
    const int tt = lane & 7;

    const float invM = 1.0f / (float)MTOT;
    float A1[3], B1[3];
#pragma unroll
    for (int a = 0; a < 3; ++a) {
        const float mean = ws[ST_OFF + a] * invM;
        const float var  = ws[ST_OFF + 3 + a] * invM - mean * mean;
        const float sc = gp[a] * rsqrtf(var + EPSb);
        A1[a] = sc; B1[a] = bp_bn[a] - mean * sc;
    }
    const float mean3 = ws[ST_OFF + 134 + tt] * invM;
    const float var3  = ws[ST_OFF + 142 + tt] * invM - mean3 * mean3;
    const float A3 = gw2[tt] * rsqrtf(var3 + EPSb);
    const float B3 = bw2_bn[tt] - mean3 * A3;
    float ww2c[8];
#pragma unroll
    for (int u = 0; u < 8; ++u) ww2c[u] = Ww2[u * 8 + tt];
    const float bw2c = bw2[tt];
    const float wp20 = Wp2[lane], wp21 = Wp2[64 + lane], wp22 = Wp2[128 + lane];
    const float bp2c = bp2[lane];
    const float* T   = ws + T_OFF;
    const float* w1p = ws + W1P_OFF;
    const u16*  xvb  = wsu + XV_US;

    const int n0 = gw * 16;
    int   il = (lane < 16) ? idx[n0 * 16 + lane] : 0;
    float tl = (lane < 48) ? T[(unsigned)n0 * 48u + lane] : 0.0f;
    float v1 = w1p[(unsigned)n0 * 128u + lane];
    float v2 = w1p[(unsigned)n0 * 128u + 64u + lane];

    for (int it = 0; it < 16; ++it) {
        const int n = n0 + it;
        const int   ilc = il;
        const float tlc = tl;
        const float v1c = v1, v2c = v2;
        if (it < 15) {
            const int nx = n + 1;
            il = (lane < 16) ? idx[nx * 16 + lane] : 0;
            tl = (lane < 48) ? T[(unsigned)nx * 48u + lane] : 0.0f;
            v1 = w1p[(unsigned)nx * 128u + lane];
            v2 = w1p[(unsigned)nx * 128u + 64u + lane];
        }
        int nb[16];
#pragma unroll
        for (int j = 0; j < 16; ++j) nb[j] = __shfl(ilc, j, 64);
        u16 xvr[16];
#pragma unroll
        for (int j = 0; j < 16; ++j) xvr[j] = xvb[(unsigned)nb[j] * 64u + lane];

        sv3[wid][lane >> 3][tt]       = fmaxf(fmaf(v1c, A3, B3), 0.0f);
        sv3[wid][(lane >> 3) + 8][tt] = fmaxf(fmaf(v2c, A3, B3), 0.0f);
        __syncthreads();
        {
            const int j1 = lane >> 3;
            float a0 = bw2c, a1 = bw2c;
#pragma unroll
            for (int u = 0; u < 8; ++u) {
                a0 = fmaf(sv3[wid][j1][u], ww2c[u], a0);
                a1 = fmaf(sv3[wid][j1 + 8][u], ww2c[u], a1);
            }
            sw2[wid][j1][tt] = a0;
            sw2[wid][j1 + 8][tt] = a1;
        }
        __syncthreads();
        float mx = -1e30f;
#pragma unroll
        for (int j = 0; j < 16; ++j) mx = fmaxf(mx, sw2[wid][j][tt]);
        float e[16];
        float sum = 0.0f;
#pragma unroll
        for (int j = 0; j < 16; ++j) { e[j] = __expf(sw2[wid][j][tt] - mx); sum += e[j]; }
        const float inv = 1.0f / sum;
        float acc = 0.0f;
#pragma unroll
        for (int j = 0; j < 16; ++j) {
            float t0 = __shfl(tlc, 3 * j + 0, 64);
            float t1 = __shfl(tlc, 3 * j + 1, 64);
            float t2 = __shfl(tlc, 3 * j + 2, 64);
            t0 = fmaxf(fmaf(t0, A1[0], B1[0]), 0.0f);
            t1 = fmaxf(fmaf(t1, A1[1], B1[1]), 0.0f);
            t2 = fmaxf(fmaf(t2, A1[2], B1[2]), 0.0f);
            const float prc = bp2c + t0 * wp20 + t1 * wp21 + t2 * wp22;
            acc = fmaf(bf2f(xvr[j]) + prc, e[j] * inv, acc);
        }
        out[(unsigned)n * 64u + lane] = acc;
        __syncthreads();
    }
}

extern "C" void kernel_launch(void* const* d_in, const int* in_sizes, int n_in,
                              void* d_out, int out_size, void* d_ws, size_t ws_size,
                              hipStream_t stream)
{
    const float* p      = (const float*)d_in[0];
    const float* x      = (const float*)d_in[1];
    const int*   idx    = (const int*)d_in[2];
    const float* Wq     = (const float*)d_in[3];
    const float* bq     = (const float*)d_in[4];
    const float* Wk     = (const float*)d_in[5];
    const float* bk     = (const float*)d_in[6];
    const float* Wv     = (const float*)d_in[7];
    const float* bv     = (const float*)d_in[8];
    const float* Wp1    = (const float*)d_in[9];
    const float* bp1    = (const float*)d_in[10];
    const float* gp     = (const float*)d_in[11];
    const float* bp_bn  = (const float*)d_in[12];
    const float* Wp2    = (const float*)d_in[13];
    const float* bp2    = (const float*)d_in[14];
    const float* gw1    = (const float*)d_in[15];
    const float* bw1_bn = (const float*)d_in[16];
    const float* Ww1    = (const float*)d_in[17];
    const float* bw1    = (const float*)d_in[18];
    const float* gw2    = (const float*)d_in[19];
    const float* bw2_bn = (const float*)d_in[20];
    const float* Ww2    = (const float*)d_in[21];
    const float* bw2    = (const float*)d_in[22];
    float* ws  = (float*)d_ws;
    float* out = (float*)d_out;
    (void)in_sizes; (void)n_in; (void)out_size; (void)ws_size;

    hipMemsetAsync((char*)d_ws + (size_t)ST_OFF * 4, 0, 150 * sizeof(float), stream);

    k1_proj_bn1<<<512, 256, 0, stream>>>(p, x, idx, Wq, bq, Wk, bk, Wv, bv, Wp1, bp1, ws);
    k2_bn2<<<1024, 256, 0, stream>>>(idx, gp, bp_bn, Wp2, bp2, ws);
    k3_w1_bn3<<<1024, 256, 0, stream>>>(gw1, bw1_bn, Ww1, bw1, ws);
    k4_final<<<1024, 256, 0, stream>>>(idx, gp, bp_bn, Wp2, bp2,
                                       gw2, bw2_bn, Ww2, bw2, ws, out);
}

// Round 5
// 314.866 us; speedup vs baseline: 1.7674x; 1.0357x over previous
//
#include <hip/hip_runtime.h>

typedef unsigned short u16;
typedef __attribute__((ext_vector_type(8))) short bf16x8;
typedef __attribute__((ext_vector_type(8))) unsigned short u16x8;
typedef __attribute__((ext_vector_type(4))) float f32x4;

#define NPTS 65536
#define MTOT 1048576            // NPTS * NS
#define EPSb 1e-5f

// ---- workspace layout ----
// float-offsets from ws base:
#define XQ_OFF  0u              // f32 [NPTS,64]            16 MB
#define T_OFF   4194304u        // f32 [MTOT,3] raw bn1 in  12 MB
#define W1P_OFF 7340032u        // f32 [MTOT,8]             32 MB
#define ST_OFF  15728640u       // f32 [150] stats
// ushort-offsets from ws base:
#define XK_US   31457792u       // bf16 [NPTS,64]            8 MB
#define DKV_US  35652096u       // bf16 [NPTS,64] (xv-xk)    8 MB
#define W0_US   39846400u       // bf16 [MTOT,64]          128 MB

__device__ __forceinline__ float bf2f(u16 h) {
    return __uint_as_float(((unsigned)h) << 16);
}
__device__ __forceinline__ u16 f2bf(float f) {
    unsigned u = __float_as_uint(f);
    u += 0x7fffu + ((u >> 16) & 1u);      // round-to-nearest-even
    return (u16)(u >> 16);
}

// ---------------------------------------------------------------------------
// K1: xq/xk/dkv projections via MFMA ([65536,64] @ [64,192] bf16) + BN1 stats.
// dkv = (xv+bv) - (xk+bk) so K4 can rebuild xv_g + pr = w0 + xq + dkv_g.
// ---------------------------------------------------------------------------
__global__ __launch_bounds__(256) void k1_proj_bn1(
    const float* __restrict__ p, const float* __restrict__ x, const int* __restrict__ idx,
    const float* __restrict__ Wq, const float* __restrict__ bq,
    const float* __restrict__ Wk, const float* __restrict__ bk,
    const float* __restrict__ Wv, const float* __restrict__ bv,
    const float* __restrict__ Wp1, const float* __restrict__ bp1,
    float* __restrict__ ws)
{
    u16* wsu = (u16*)ws;
    __shared__ float sred[6];
    const int tid   = threadIdx.x;
    const int lane  = tid & 63;
    const int wid   = tid >> 6;
    const int col16 = lane & 15;
    const int quad  = lane >> 4;
    if (tid < 6) sred[tid] = 0.0f;
    __syncthreads();

    // ---- load B fragments: B[k=quad*8+j][n=16t+col16], bf16 ----
    const float* Wm[3] = { Wq, Wk, Wv };
    bf16x8 bf[3][4][2];
#pragma unroll
    for (int M = 0; M < 3; ++M)
#pragma unroll
        for (int t = 0; t < 4; ++t)
#pragma unroll
            for (int h = 0; h < 2; ++h) {
                bf16x8 tmp;
#pragma unroll
                for (int j = 0; j < 8; ++j)
                    tmp[j] = (short)f2bf(Wm[M][(h * 32 + quad * 8 + j) * 64 + t * 16 + col16]);
                bf[M][t][h] = tmp;
            }
    float bq_t[4], bk_t[4], bv_t[4];
#pragma unroll
    for (int t = 0; t < 4; ++t) {
        bq_t[t] = bq[t * 16 + col16];
        bk_t[t] = bk[t * 16 + col16];
        bv_t[t] = bv[t * 16 + col16];
    }

    float* xq   = ws + XQ_OFF;
    u16*  xkb   = wsu + XK_US;
    u16*  dkvb  = wsu + DKV_US;

    const int gw = blockIdx.x * 4 + wid;              // 0..2047
#pragma unroll
    for (int g = 0; g < 2; ++g) {
        const int n0 = (gw * 2 + g) * 16;
        const float* xrow = x + (unsigned)(n0 + col16) * 64u;
        const float4 fa0 = *(const float4*)&xrow[quad * 8];
        const float4 fa1 = *(const float4*)&xrow[quad * 8 + 4];
        const float4 fb0 = *(const float4*)&xrow[32 + quad * 8];
        const float4 fb1 = *(const float4*)&xrow[32 + quad * 8 + 4];
        bf16x8 a0, a1;
        a0[0] = (short)f2bf(fa0.x); a0[1] = (short)f2bf(fa0.y);
        a0[2] = (short)f2bf(fa0.z); a0[3] = (short)f2bf(fa0.w);
        a0[4] = (short)f2bf(fa1.x); a0[5] = (short)f2bf(fa1.y);
        a0[6] = (short)f2bf(fa1.z); a0[7] = (short)f2bf(fa1.w);
        a1[0] = (short)f2bf(fb0.x); a1[1] = (short)f2bf(fb0.y);
        a1[2] = (short)f2bf(fb0.z); a1[3] = (short)f2bf(fb0.w);
        a1[4] = (short)f2bf(fb1.x); a1[5] = (short)f2bf(fb1.y);
        a1[6] = (short)f2bf(fb1.z); a1[7] = (short)f2bf(fb1.w);

#pragma unroll
        for (int t = 0; t < 4; ++t) {
            f32x4 aq = {0,0,0,0}, ak = {0,0,0,0}, av = {0,0,0,0};
            aq = __builtin_amdgcn_mfma_f32_16x16x32_bf16(a0, bf[0][t][0], aq, 0, 0, 0);
            aq = __builtin_amdgcn_mfma_f32_16x16x32_bf16(a1, bf[0][t][1], aq, 0, 0, 0);
            ak = __builtin_amdgcn_mfma_f32_16x16x32_bf16(a0, bf[1][t][0], ak, 0, 0, 0);
            ak = __builtin_amdgcn_mfma_f32_16x16x32_bf16(a1, bf[1][t][1], ak, 0, 0, 0);
            av = __builtin_amdgcn_mfma_f32_16x16x32_bf16(a0, bf[2][t][0], av, 0, 0, 0);
            av = __builtin_amdgcn_mfma_f32_16x16x32_bf16(a1, bf[2][t][1], av, 0, 0, 0);
#pragma unroll
            for (int r = 0; r < 4; ++r) {
                const unsigned row = (unsigned)(n0 + quad * 4 + r);
                const unsigned o   = row * 64u + (unsigned)(t * 16 + col16);
                const float qv = aq[r] + bq_t[t];
                const float kv = ak[r] + bk_t[t];
                const float vv = av[r] + bv_t[t];
                xq[o]   = qv;
                xkb[o]  = f2bf(kv);
                dkvb[o] = f2bf(vv - kv);
            }
        }
    }

    // ---- BN1 stats + store raw T: this block's 2048 pairs ----
    const int base = blockIdx.x * 128;
    const float w00 = Wp1[0], w01 = Wp1[1], w02 = Wp1[2];
    const float w10 = Wp1[3], w11 = Wp1[4], w12 = Wp1[5];
    const float w20 = Wp1[6], w21 = Wp1[7], w22 = Wp1[8];
    const float c0 = bp1[0], c1 = bp1[1], c2 = bp1[2];
    float s0 = 0, s1 = 0, s2 = 0, q0 = 0, q1 = 0, q2 = 0;
#pragma unroll
    for (int m = 0; m < 8; ++m) {
        const int pl = tid + m * 256;            // 0..2047
        const int n  = base + (pl >> 4);
        const unsigned gpair = (unsigned)(base * 16 + pl);
        const int nb = idx[gpair];
        const float r0 = p[nb * 3 + 0] - p[n * 3 + 0];
        const float r1 = p[nb * 3 + 1] - p[n * 3 + 1];
        const float r2 = p[nb * 3 + 2] - p[n * 3 + 2];
        const float t0 = c0 + r0 * w00 + r1 * w10 + r2 * w20;
        const float t1 = c1 + r0 * w01 + r1 * w11 + r2 * w21;
        const float t2 = c2 + r0 * w02 + r1 * w12 + r2 * w22;
        ws[T_OFF + gpair * 3u + 0u] = t0;
        ws[T_OFF + gpair * 3u + 1u] = t1;
        ws[T_OFF + gpair * 3u + 2u] = t2;
        s0 += t0; s1 += t1; s2 += t2;
        q0 += t0 * t0; q1 += t1 * t1; q2 += t2 * t2;
    }
    atomicAdd(&sred[0], s0); atomicAdd(&sred[1], s1); atomicAdd(&sred[2], s2);
    atomicAdd(&sred[3], q0); atomicAdd(&sred[4], q1); atomicAdd(&sred[5], q2);
    __syncthreads();
    if (tid < 6) atomicAdd(&ws[ST_OFF + tid], sred[tid]);
}

// ---------------------------------------------------------------------------
// K2: w0 = xk[idx] - xq + pr ; store w0 bf16 ; BN2 stats.
// T pre-relu'd per lane once; xk gather pipelined one point ahead.
// ---------------------------------------------------------------------------
__global__ __launch_bounds__(256) void k2_bn2(
    const int* __restrict__ idx,
    const float* __restrict__ gp, const float* __restrict__ bp_bn,
    const float* __restrict__ Wp2, const float* __restrict__ bp2,
    float* __restrict__ ws)
{
    u16* wsu = (u16*)ws;
    __shared__ float ss[64], sq[64];
    const int tid = threadIdx.x;
    const int lane = tid & 63;
    const int gw = blockIdx.x * 4 + (tid >> 6);
    if (tid < 64) { ss[tid] = 0.0f; sq[tid] = 0.0f; }

    const float invM = 1.0f / (float)MTOT;
    float A1[3], B1[3];
#pragma unroll
    for (int a = 0; a < 3; ++a) {
        const float mean = ws[ST_OFF + a] * invM;
        const float var  = ws[ST_OFF + 3 + a] * invM - mean * mean;
        const float sc = gp[a] * rsqrtf(var + EPSb);
        A1[a] = sc; B1[a] = bp_bn[a] - mean * sc;
    }
    const int comp = lane % 3;                 // lane's T component
    const float A1c = A1[comp], B1c = B1[comp];
    const float wp20 = Wp2[lane], wp21 = Wp2[64 + lane], wp22 = Wp2[128 + lane];
    const float bp2c = bp2[lane];
    const float* xq  = ws + XQ_OFF;
    const float* T   = ws + T_OFF;
    const u16*  xkb  = wsu + XK_US;
    u16*        w0b  = wsu + W0_US;

    float s = 0.0f, q = 0.0f;
    const int n0 = gw * 16;

    // prologue: point n0
    int il0 = (lane < 16) ? idx[n0 * 16 + lane] : 0;
    int nbp[16];
#pragma unroll
    for (int j = 0; j < 16; ++j) nbp[j] = __shfl(il0, j, 64);
    u16 krc[16];
#pragma unroll
    for (int j = 0; j < 16; ++j) krc[j] = xkb[(unsigned)nbp[j] * 64u + lane];
    float tr0  = (lane < 48) ? T[(unsigned)n0 * 48u + lane] : 0.0f;
    float trlc = fmaxf(fmaf(tr0, A1c, B1c), 0.0f);
    float xqc  = xq[(unsigned)n0 * 64u + lane];

    for (int nn = 0; nn < 16; ++nn) {
        const int n  = n0 + nn;
        const int nx = (nn < 15) ? n + 1 : n;
        // prefetch next point (redundant at nn==15, always in-bounds)
        const int il2 = (lane < 16) ? idx[nx * 16 + lane] : 0;
        int nb2[16];
#pragma unroll
        for (int j = 0; j < 16; ++j) nb2[j] = __shfl(il2, j, 64);
        u16 krn[16];
#pragma unroll
        for (int j = 0; j < 16; ++j) krn[j] = xkb[(unsigned)nb2[j] * 64u + lane];
        const float trn0 = (lane < 48) ? T[(unsigned)nx * 48u + lane] : 0.0f;
        const float trln = fmaxf(fmaf(trn0, A1c, B1c), 0.0f);
        const float xqn  = xq[(unsigned)nx * 64u + lane];

        // compute current point with krc (loads issued last iteration)
#pragma unroll
        for (int j = 0; j < 16; ++j) {
            const float t0 = __shfl(trlc, 3 * j + 0, 64);
            const float t1 = __shfl(trlc, 3 * j + 1, 64);
            const float t2 = __shfl(trlc, 3 * j + 2, 64);
            const float prc = bp2c + t0 * wp20 + t1 * wp21 + t2 * wp22;
            const float w0 = bf2f(krc[j]) - xqc + prc;
            s += w0; q = fmaf(w0, w0, q);
            w0b[(unsigned)(n * 16 + j) * 64u + lane] = f2bf(w0);
        }
#pragma unroll
        for (int j = 0; j < 16; ++j) krc[j] = krn[j];
        trlc = trln; xqc = xqn;
    }
    __syncthreads();
    atomicAdd(&ss[lane], s); atomicAdd(&sq[lane], q);
    __syncthreads();
    if (tid < 64) {
        atomicAdd(&ws[ST_OFF + 6 + tid], ss[tid]);
        atomicAdd(&ws[ST_OFF + 70 + tid], sq[tid]);
    }
}

// ---------------------------------------------------------------------------
// K3: w1' = relu(bn2(w0)) @ Ww1 + bw1 via MFMA, barrier-free, no LDS staging.
// ---------------------------------------------------------------------------
__global__ __launch_bounds__(256) void k3_w1_bn3(
    const float* __restrict__ gw1, const float* __restrict__ bw1_bn,
    const float* __restrict__ Ww1, const float* __restrict__ bw1,
    float* __restrict__ ws)
{
    u16* wsu = (u16*)ws;
    __shared__ float s3r[8], q3r[8];
    const int tid   = threadIdx.x;
    const int lane  = tid & 63;
    const int wid   = tid >> 6;
    const int col16 = lane & 15;
    const int quad  = lane >> 4;
    if (tid < 8) { s3r[tid] = 0.0f; q3r[tid] = 0.0f; }
    __syncthreads();

    const float invM = 1.0f / (float)MTOT;
    float A2q[8], B2q[8], A2h[8], B2h[8];
#pragma unroll
    for (int j = 0; j < 8; ++j) {
        {
            const int c = quad * 8 + j;
            const float mean = ws[ST_OFF + 6 + c] * invM;
            const float var  = ws[ST_OFF + 70 + c] * invM - mean * mean;
            A2q[j] = gw1[c] * rsqrtf(var + EPSb);
            B2q[j] = bw1_bn[c] - mean * A2q[j];
        }
        {
            const int c = 32 + quad * 8 + j;
            const float mean = ws[ST_OFF + 6 + c] * invM;
            const float var  = ws[ST_OFF + 70 + c] * invM - mean * mean;
            A2h[j] = gw1[c] * rsqrtf(var + EPSb);
            B2h[j] = bw1_bn[c] - mean * A2h[j];
        }
    }
    bf16x8 b0, b1;
#pragma unroll
    for (int j = 0; j < 8; ++j) {
        const int k0 = quad * 8 + j;
        b0[j] = (col16 < 8) ? (short)f2bf(Ww1[k0 * 8 + col16]) : (short)0;
        b1[j] = (col16 < 8) ? (short)f2bf(Ww1[(k0 + 32) * 8 + col16]) : (short)0;
    }
    const float bw1c = (col16 < 8) ? bw1[col16] : 0.0f;

    const u16* w0b = wsu + W0_US;
    float* w1p = ws + W1P_OFF;
    const int wgid = blockIdx.x * 4 + wid;            // 0..4095
    float bs = 0.0f, bq2 = 0.0f;

#pragma unroll 2
    for (int t = 0; t < 16; ++t) {
        const int pair0 = (wgid * 16 + t) * 16;
        const u16* rowp = w0b + (unsigned)(pair0 + col16) * 64u;
        const u16x8 r0 = *(const u16x8*)(rowp + quad * 8);
        const u16x8 r1 = *(const u16x8*)(rowp + 32 + quad * 8);
        bf16x8 a0, a1;
#pragma unroll
        for (int j = 0; j < 8; ++j) {
            float f0 = fmaxf(fmaf(bf2f(r0[j]), A2q[j], B2q[j]), 0.0f);
            float f1 = fmaxf(fmaf(bf2f(r1[j]), A2h[j], B2h[j]), 0.0f);
            a0[j] = (short)f2bf(f0);
            a1[j] = (short)f2bf(f1);
        }
        f32x4 acc = {0.0f, 0.0f, 0.0f, 0.0f};
        acc = __builtin_amdgcn_mfma_f32_16x16x32_bf16(a0, b0, acc, 0, 0, 0);
        acc = __builtin_amdgcn_mfma_f32_16x16x32_bf16(a1, b1, acc, 0, 0, 0);
        if (col16 < 8) {
#pragma unroll
            for (int r = 0; r < 4; ++r) {
                const float o = acc[r] + bw1c;
                w1p[(unsigned)(pair0 + quad * 4 + r) * 8u + (unsigned)col16] = o;
                bs += o;
                bq2 = fmaf(o, o, bq2);
            }
        }
    }
    if (col16 < 8) {
        atomicAdd(&s3r[col16], bs);
        atomicAdd(&q3r[col16], bq2);
    }
    __syncthreads();
    if (tid < 8) {
        atomicAdd(&ws[ST_OFF + 134 + tid], s3r[tid]);
        atomicAdd(&ws[ST_OFF + 142 + tid], q3r[tid]);
    }
}

// ---------------------------------------------------------------------------
// K4: bn3 -> relu -> @Ww2 -> softmax -> aggregate using u = w0 + xq + dkv_g.
// Wave-private LDS (no barriers); dkv gather pipelined one point ahead.
// ---------------------------------------------------------------------------
__global__ __launch_bounds__(256) void k4_final(
    const int* __restrict__ idx,
    const float* __restrict__ gw2, const float* __restrict__ bw2_bn,
    const float* __restrict__ Ww2, const float* __restrict__ bw2,
    const float* __restrict__ ws, float* __restrict__ out)
{
    const u16* wsu = (const u16*)ws;
    __shared__ float sv3[4][16][8];
    __shared__ float sw2[4][16][8];
    const int tid = threadIdx.x;
    const int lane = tid & 63;
    const int wid = tid >> 6;
    const int gw = blockIdx.x * 4 + wid;
    const int tt = lane & 7;
    const int j1 = lane >> 3;

    const float invM = 1.0f / (float)MTOT;
    const float mean3 = ws[ST_OFF + 134 + tt] * invM;
    const float var3  = ws[ST_OFF + 142 + tt] * invM - mean3 * mean3;
    const float A3 = gw2[tt] * rsqrtf(var3 + EPSb);
    const float B3 = bw2_bn[tt] - mean3 * A3;
    float ww2c[8];
#pragma unroll
    for (int u = 0; u < 8; ++u) ww2c[u] = Ww2[u * 8 + tt];
    const float bw2c = bw2[tt];

    const float* xq  = ws + XQ_OFF;
    const float* w1p = ws + W1P_OFF;
    const u16*  dkvb = wsu + DKV_US;
    const u16*  w0b  = wsu + W0_US;

    const int n0 = gw * 16;
    // prologue: point n0's gathers
    int il0 = (lane < 16) ? idx[n0 * 16 + lane] : 0;
    int nbp[16];
#pragma unroll
    for (int j = 0; j < 16; ++j) nbp[j] = __shfl(il0, j, 64);
    u16 dkc[16];
#pragma unroll
    for (int j = 0; j < 16; ++j) dkc[j] = dkvb[(unsigned)nbp[j] * 64u + lane];
    float v1  = w1p[(unsigned)n0 * 128u + lane];
    float v2  = w1p[(unsigned)n0 * 128u + 64u + lane];
    float xqc = xq[(unsigned)n0 * 64u + lane];

    for (int it = 0; it < 16; ++it) {
        const int n  = n0 + it;
        const int nx = (it < 15) ? n + 1 : n;

        // issue current point's w0 row loads (coalesced, L3-warm from K3)
        u16 w0r[16];
#pragma unroll
        for (int j = 0; j < 16; ++j) w0r[j] = w0b[(unsigned)(n * 16 + j) * 64u + lane];

        // prefetch next point
        const int il2 = (lane < 16) ? idx[nx * 16 + lane] : 0;
        int nb2[16];
#pragma unroll
        for (int j = 0; j < 16; ++j) nb2[j] = __shfl(il2, j, 64);
        u16 dkn[16];
#pragma unroll
        for (int j = 0; j < 16; ++j) dkn[j] = dkvb[(unsigned)nb2[j] * 64u + lane];
        const float v1n  = w1p[(unsigned)nx * 128u + lane];
        const float v2n  = w1p[(unsigned)nx * 128u + 64u + lane];
        const float xqn  = xq[(unsigned)nx * 64u + lane];

        // bn3 -> relu -> 8x8 matmul (wave-private LDS, compiler lgkmcnt orders)
        sv3[wid][j1][tt]     = fmaxf(fmaf(v1, A3, B3), 0.0f);
        sv3[wid][j1 + 8][tt] = fmaxf(fmaf(v2, A3, B3), 0.0f);
        {
            float a0 = bw2c, a1 = bw2c;
#pragma unroll
            for (int u = 0; u < 8; ++u) {
                a0 = fmaf(sv3[wid][j1][u], ww2c[u], a0);
                a1 = fmaf(sv3[wid][j1 + 8][u], ww2c[u], a1);
            }
            sw2[wid][j1][tt]     = a0;
            sw2[wid][j1 + 8][tt] = a1;
        }
        // softmax over 16 neighbors (per-lane, reads wave-private LDS)
        float mx = -1e30f;
#pragma unroll
        for (int j = 0; j < 16; ++j) mx = fmaxf(mx, sw2[wid][j][tt]);
        float e[16];
        float sum = 0.0f;
#pragma unroll
        for (int j = 0; j < 16; ++j) { e[j] = __expf(sw2[wid][j][tt] - mx); sum += e[j]; }

        // aggregate: u = w0 + xq + dkv
        float acc = 0.0f;
#pragma unroll
        for (int j = 0; j < 16; ++j) {
            const float uu = (bf2f(w0r[j]) + xqc) + bf2f(dkc[j]);
            acc = fmaf(uu, e[j], acc);
        }
        out[(unsigned)n * 64u + lane] = acc * (1.0f / sum);

        // rotate pipeline
#pragma unroll
        for (int j = 0; j < 16; ++j) dkc[j] = dkn[j];
        v1 = v1n; v2 = v2n; xqc = xqn;
    }
}

extern "C" void kernel_launch(void* const* d_in, const int* in_sizes, int n_in,
                              void* d_out, int out_size, void* d_ws, size_t ws_size,
                              hipStream_t stream)
{
    const float* p      = (const float*)d_in[0];
    const float* x      = (const float*)d_in[1];
    const int*   idx    = (const int*)d_in[2];
    const float* Wq     = (const float*)d_in[3];
    const float* bq     = (const float*)d_in[4];
    const float* Wk     = (const float*)d_in[5];
    const float* bk     = (const float*)d_in[6];
    const float* Wv     = (const float*)d_in[7];
    const float* bv     = (const float*)d_in[8];
    const float* Wp1    = (const float*)d_in[9];
    const float* bp1    = (const float*)d_in[10];
    const float* gp     = (const float*)d_in[11];
    const float* bp_bn  = (const float*)d_in[12];
    const float* Wp2    = (const float*)d_in[13];
    const float* bp2    = (const float*)d_in[14];
    const float* gw1    = (const float*)d_in[15];
    const float* bw1_bn = (const float*)d_in[16];
    const float* Ww1    = (const float*)d_in[17];
    const float* bw1    = (const float*)d_in[18];
    const float* gw2    = (const float*)d_in[19];
    const float* bw2_bn = (const float*)d_in[20];
    const float* Ww2    = (const float*)d_in[21];
    const float* bw2    = (const float*)d_in[22];
    float* ws  = (float*)d_ws;
    float* out = (float*)d_out;
    (void)in_sizes; (void)n_in; (void)out_size; (void)ws_size;

    hipMemsetAsync((char*)d_ws + (size_t)ST_OFF * 4, 0, 150 * sizeof(float), stream);

    k1_proj_bn1<<<512, 256, 0, stream>>>(p, x, idx, Wq, bq, Wk, bk, Wv, bv, Wp1, bp1, ws);
    k2_bn2<<<1024, 256, 0, stream>>>(idx, gp, bp_bn, Wp2, bp2, ws);
    k3_w1_bn3<<<1024, 256, 0, stream>>>(gw1, bw1_bn, Ww1, bw1, ws);
    k4_final<<<1024, 256, 0, stream>>>(idx, gw2, bw2_bn, Ww2, bw2, ws, out);
}